// Round 16
// baseline (582.763 us; speedup 1.0000x reference)
//
#include <hip/hip_runtime.h>
#include <math.h>

#define B_ 16
#define S_ 2048
#define H_ 12
#define D_ 64
#define HID 768
#define A_ 40
#define SCALE_ 0.125f
#define CH1 8          // stage1 s-chunks per (b,h)
#define SUBT 64        // s per subtile
#define NSUB 4         // subtiles per block (256 s per block)

typedef __attribute__((ext_vector_type(8))) short short8v;    // 8 bf16 (4 VGPR)
typedef __attribute__((ext_vector_type(4))) float f32x4;
typedef __attribute__((ext_vector_type(16))) float f32x16;    // 32x32 MFMA C/D

__device__ __forceinline__ unsigned f2bf_bits(float x) {
    unsigned u = __float_as_uint(x);
    return (u + 0x7FFFu + ((u >> 16) & 1u)) >> 16;   // RTNE
}

__device__ __forceinline__ void split1(float v, unsigned short& h, unsigned short& l) {
    __bf16 bh = (__bf16)v;
    float hf = (float)bh;
    __bf16 bl = (__bf16)(v - hf);
    h = __builtin_bit_cast(unsigned short, bh);
    l = __builtin_bit_cast(unsigned short, bl);
}

// split 8 fp32 -> hi/lo bf16 via native __bf16 casts (RTNE)
__device__ __forceinline__ void split8c(const float* x, int4& hi, int4& lo) {
    unsigned h[8], l[8];
#pragma unroll
    for (int i = 0; i < 8; i++) {
        __bf16 bh = (__bf16)x[i];
        float hf = (float)bh;
        __bf16 bl = (__bf16)(x[i] - hf);
        h[i] = (unsigned)__builtin_bit_cast(unsigned short, bh);
        l[i] = (unsigned)__builtin_bit_cast(unsigned short, bl);
    }
    hi = make_int4((int)(h[0] | (h[1] << 16)), (int)(h[2] | (h[3] << 16)),
                   (int)(h[4] | (h[5] << 16)), (int)(h[6] | (h[7] << 16)));
    lo = make_int4((int)(l[0] | (l[1] << 16)), (int)(l[2] | (l[3] << 16)),
                   (int)(l[4] | (l[5] << 16)), (int)(l[6] | (l[7] << 16)));
}

// ------- merged input preconvert: W transpose/split + dist frag tables ----------
// blocks [0,1728): wt_convert; [1728,1856): dist_frag (stage2); [1856,1922): dist_frag0
#define WT_BLKS 1728   // 3*192*768 / 256
#define DF_BLKS 128    // 256*2*64 / 256
#define D0_BLKS 66     // ceil(131*2*64 / 256)
__global__ __launch_bounds__(256) void preconvert(
    const float* __restrict__ Wq, const float* __restrict__ Wk, const float* __restrict__ Wv,
    const float* __restrict__ dist,
    unsigned short* __restrict__ Wth, unsigned short* __restrict__ Wtl,
    unsigned short* __restrict__ DFh, unsigned short* __restrict__ DFl,
    unsigned short* __restrict__ D0h, unsigned short* __restrict__ D0l)
{
    const int bx = blockIdx.x;
    const int t = threadIdx.x;
    if (bx < WT_BLKS) {
        int idx = bx * 256 + t;                       // < 3*192*768
        if (idx >= 3 * 192 * 768) return;
        int n  = idx % 768;
        int kc = (idx / 768) % 192;
        int z  = idx / (768 * 192);
        const float* W = (z == 0) ? Wq : (z == 1) ? Wk : Wv;
        unsigned short h4[4], l4[4];
#pragma unroll
        for (int i = 0; i < 4; i++) {
            float x = W[(size_t)(4 * kc + i) * HID + n];
            unsigned hb = f2bf_bits(x);
            float hf = __uint_as_float(hb << 16);
            h4[i] = (unsigned short)hb;
            l4[i] = (unsigned short)f2bf_bits(x - hf);
        }
        size_t o = ((size_t)z * HID + n) * HID + 4 * kc;
        *(ushort4*)&Wth[o] = make_ushort4(h4[0], h4[1], h4[2], h4[3]);
        *(ushort4*)&Wtl[o] = make_ushort4(l4[0], l4[1], l4[2], l4[3]);
    } else if (bx < WT_BLKS + DF_BLKS) {
        int g = (bx - WT_BLKS) * 256 + t;             // < 256*2*64
        int lane = g & 63;
        int ks = (g >> 6) & 1;
        int u  = g >> 7;
        int row = 8 + u * 16 + (lane & 15);
        int col = ks * 32 + ((lane >> 4) << 3);
        float xv[8];
#pragma unroll
        for (int j = 0; j < 8; j++)
            xv[j] = (row < 4095) ? dist[(size_t)row * D_ + col + j] : 0.f;
        int4 hi, lo;
        split8c(xv, hi, lo);
        *(int4*)&DFh[(size_t)g * 8] = hi;
        *(int4*)&DFl[(size_t)g * 8] = lo;
    } else {
        int g = (bx - WT_BLKS - DF_BLKS) * 256 + t;   // < 131*2*64
        if (g >= 131 * 2 * 64) return;
        int lane = g & 63;
        int ks = (g >> 6) & 1;
        int u  = g >> 7;
        int row = u * 16 + (lane & 15);               // <= 2095, all real
        int col = ks * 32 + ((lane >> 4) << 3);
        float xv[8];
#pragma unroll
        for (int j = 0; j < 8; j++) xv[j] = dist[(size_t)row * D_ + col + j];
        int4 hi, lo;
        split8c(xv, hi, lo);
        *(int4*)&D0h[(size_t)g * 8] = hi;
        *(int4*)&D0l[(size_t)g * 8] = lo;
    }
}

// ------- AgV^T -> fragment-major: [bh][nt<4][ks][lane][8] rows=d, cols=a ----------
__global__ void avt_frag(const float* __restrict__ AgV,
                         unsigned short* __restrict__ Vh, unsigned short* __restrict__ Vl)
{
    int g = blockIdx.x * 256 + threadIdx.x;   // 192*4*2*64
    if (g >= 192 * 4 * 2 * 64) return;
    int lane = g & 63;
    int r = g >> 6;
    int ks = r & 1; r >>= 1;
    int nt = r & 3;
    int bh = r >> 2;
    int d = nt * 16 + (lane & 15);
    int a0 = ks * 32 + ((lane >> 4) << 3);
    float xv[8];
#pragma unroll
    for (int j = 0; j < 8; j++) {
        int a = a0 + j;
        xv[j] = (a < A_) ? AgV[((size_t)bh * A_ + a) * D_ + d] : 0.f;
    }
    int4 hi, lo;
    split8c(xv, hi, lo);
    *(int4*)&Vh[(size_t)g * 8] = hi;
    *(int4*)&Vl[(size_t)g * 8] = lo;
}

// ---------------- QKV: bf16x3 MFMA GEMM (32x32x16), 128x256 tile, XCD-swizzled ----------
__global__ __launch_bounds__(512, 2) void qkv_z(
    const float* __restrict__ X,
    const unsigned short* __restrict__ Wth, const unsigned short* __restrict__ Wtl,
    const float* __restrict__ bq, const float* __restrict__ bk, const float* __restrict__ bv,
    float* __restrict__ Q, float* __restrict__ K, float* __restrict__ V)
{
    const int L   = blockIdx.x;
    const int k8  = L & 7, sl_ = L >> 3;
    const int mt  = k8 * 32 + sl_ / 9;
    const int sub = sl_ % 9;
    const int nt  = sub % 3, zz = sub / 3;
    const int m0 = mt * 128, n0 = nt * 256;

    const float* __restrict__ bias = (zz == 0) ? bq : (zz == 1) ? bk : bv;
    float* __restrict__ Out        = (zz == 0) ? Q  : (zz == 1) ? K  : V;
    const unsigned short* __restrict__ Bhg = Wth + (size_t)zz * HID * HID;
    const unsigned short* __restrict__ Blg = Wtl + (size_t)zz * HID * HID;

    __shared__ unsigned short Ah[128][40];
    __shared__ unsigned short Al[128][40];
    __shared__ unsigned short Bh[256][40];
    __shared__ unsigned short Bl[256][40];

    const int t = threadIdx.x;
    const int lane = t & 63, w = t >> 6;
    const int wm = (w & 1) * 64, wn = (w >> 1) * 64;
    const int r32 = lane & 31, kh = lane >> 5;

    const int sr = t >> 2, sca = (t & 3) * 8;
    const int sb = t >> 1, scb = (t & 1) * 16;

    f32x16 acc[2][2];
#pragma unroll
    for (int i = 0; i < 2; i++)
#pragma unroll
        for (int j = 0; j < 2; j++)
#pragma unroll
            for (int p = 0; p < 16; p++) acc[i][j][p] = 0.f;

    for (int k0 = 0; k0 < HID; k0 += 32) {
        float xv[8];
        const float* xp = X + (size_t)(m0 + sr) * HID + k0 + sca;
        float4 f0 = *(const float4*)xp;
        float4 f1 = *(const float4*)(xp + 4);
        xv[0] = f0.x; xv[1] = f0.y; xv[2] = f0.z; xv[3] = f0.w;
        xv[4] = f1.x; xv[5] = f1.y; xv[6] = f1.z; xv[7] = f1.w;
        int4 ah, al;
        split8c(xv, ah, al);
        size_t bo = (size_t)(n0 + sb) * HID + k0 + scb;
        int4 bh0 = *(const int4*)&Bhg[bo];
        int4 bh1 = *(const int4*)&Bhg[bo + 8];
        int4 bl0 = *(const int4*)&Blg[bo];
        int4 bl1 = *(const int4*)&Blg[bo + 8];

        __syncthreads();
        *(int4*)&Ah[sr][sca] = ah;
        *(int4*)&Al[sr][sca] = al;
        *(int4*)&Bh[sb][scb]     = bh0;  *(int4*)&Bh[sb][scb + 8] = bh1;
        *(int4*)&Bl[sb][scb]     = bl0;  *(int4*)&Bl[sb][scb + 8] = bl1;
        __syncthreads();

#pragma unroll
        for (int ks = 0; ks < 2; ks++) {
            const int ko = ks * 16 + kh * 8;
            short8v a_h[2], a_l[2], b_h[2], b_l[2];
#pragma unroll
            for (int i = 0; i < 2; i++) {
                a_h[i] = *(const short8v*)&Ah[wm + i * 32 + r32][ko];
                a_l[i] = *(const short8v*)&Al[wm + i * 32 + r32][ko];
                b_h[i] = *(const short8v*)&Bh[wn + i * 32 + r32][ko];
                b_l[i] = *(const short8v*)&Bl[wn + i * 32 + r32][ko];
            }
#pragma unroll
            for (int i = 0; i < 2; i++)
#pragma unroll
                for (int j = 0; j < 2; j++) {
                    acc[i][j] = __builtin_amdgcn_mfma_f32_32x32x16_bf16(a_h[i], b_h[j], acc[i][j], 0, 0, 0);
                    acc[i][j] = __builtin_amdgcn_mfma_f32_32x32x16_bf16(a_l[i], b_h[j], acc[i][j], 0, 0, 0);
                    acc[i][j] = __builtin_amdgcn_mfma_f32_32x32x16_bf16(a_h[i], b_l[j], acc[i][j], 0, 0, 0);
                }
        }
    }

    const float scl = (zz == 1) ? SCALE_ : 1.0f;
#pragma unroll
    for (int j = 0; j < 2; j++) {
        int n = n0 + wn + j * 32 + r32;
        float bj = bias[n];
        int h = n >> 6, d = n & 63;
#pragma unroll
        for (int i = 0; i < 2; i++) {
#pragma unroll
            for (int p = 0; p < 16; p++) {
                int m = m0 + wm + i * 32 + (p & 3) + 8 * (p >> 2) + 4 * kh;
                int b = m >> 11, s = m & 2047;
                Out[(((size_t)b * H_ + h) * S_ + s) * D_ + d] = (acc[i][j][p] + bj) * scl;
            }
        }
    }
}

// ------- agent pooling + AG fragment tables (Agent lives only in LDS) ----------
__global__ __launch_bounds__(256) void agpool_frag(
    const float* __restrict__ Q,
    unsigned short* __restrict__ AGFh, unsigned short* __restrict__ AGFl,
    unsigned short* __restrict__ AG1h, unsigned short* __restrict__ AG1l)
{
    const int bh = blockIdx.x;
    const int t = threadIdx.x;
    __shared__ float ag[A_][D_];
    const float* base = Q + (size_t)bh * (S_ * D_);
    for (int i = t; i < A_ * D_; i += 256) {
        int d = i & 63, a = i >> 6;
        float src = ((float)a + 0.5f) * (2048.0f / 40.0f) - 0.5f;
        src = fminf(fmaxf(src, 0.0f), 2047.0f);
        int lo = (int)floorf(src);
        int hi = min(lo + 1, S_ - 1);
        float w = src - (float)lo;
        ag[a][d] = base[lo * D_ + d] * (1.0f - w) + base[hi * D_ + d] * w;
    }
    __syncthreads();
    for (int g = t; g < 384; g += 256) {
        int lane = g & 63;
        int ks = (g >> 6) & 1;
        int at = g >> 7;
        int a = at * 16 + (lane & 15);
        int col = ks * 32 + ((lane >> 4) << 3);
        float xs[8], x1[8];
#pragma unroll
        for (int j = 0; j < 8; j++) {
            float v = (a < A_) ? ag[a][col + j] : 0.f;
            x1[j] = v; xs[j] = v * SCALE_;
        }
        int4 h1, l1, h2, l2;
        split8c(xs, h1, l1);
        split8c(x1, h2, l2);
        size_t o = ((((size_t)bh * 3 + at) * 2 + ks) * 64 + lane) * 8;
        *(int4*)&AGFh[o] = h1;  *(int4*)&AGFl[o] = l1;
        *(int4*)&AG1h[o] = h2;  *(int4*)&AG1l[o] = l2;
    }
}

// ---------------- stage 1 MFMA (round-13 proven) ----------------
__global__ __launch_bounds__(256, 2) void stage1_mfma(
    const float* __restrict__ Kl, const float* __restrict__ Vl,
    const unsigned short* __restrict__ AG1h, const unsigned short* __restrict__ AG1l,
    const unsigned short* __restrict__ D0h,  const unsigned short* __restrict__ D0l,
    const float* __restrict__ mask,
    float* __restrict__ Pacc, float* __restrict__ Pm, float* __restrict__ Pl)
{
    const int q  = blockIdx.x;       // 0..7
    const int bh = blockIdx.y;       // 0..191
    const int b  = bh / H_;
    const int s0 = q * (NSUB * SUBT);
    const float* __restrict__ kb = Kl + (size_t)bh * (S_ * D_);
    const float* __restrict__ vb = Vl + (size_t)bh * (S_ * D_);

    __shared__ unsigned short KFh[4096], KFl[4096];
    __shared__ unsigned short VTh[4096], VTl[4096];
    __shared__ float sc[SUBT][52];
    __shared__ float scp[112][52];
    __shared__ float pm6[6][A_];
    __shared__ float mrow[A_], lrow[A_], resc[A_], mrw[SUBT];

    const int t = threadIdx.x;
    const int lane = t & 63, w = t >> 6;
    const int fr = lane & 15, kg = lane >> 4;

    if (t < A_) { mrow[t] = -INFINITY; lrow[t] = 0.0f; }

    f32x4 acc3[3];
#pragma unroll
    for (int at = 0; at < 3; at++) acc3[at] = (f32x4){0.f, 0.f, 0.f, 0.f};

    for (int st = 0; st < NSUB; st++) {
        const int sb = s0 + st * SUBT;
        const int u0 = (1984 - sb) >> 4;

        __syncthreads();

        {
            const int r = t >> 2, c0 = (t & 3) * 16;
            const float* kp = kb + (size_t)(sb + r) * D_ + c0;
            float xa[8], xb[8];
            float4 f0 = *(const float4*)(kp);
            float4 f1 = *(const float4*)(kp + 4);
            float4 f2 = *(const float4*)(kp + 8);
            float4 f3 = *(const float4*)(kp + 12);
            xa[0]=f0.x; xa[1]=f0.y; xa[2]=f0.z; xa[3]=f0.w;
            xa[4]=f1.x; xa[5]=f1.y; xa[6]=f1.z; xa[7]=f1.w;
            xb[0]=f2.x; xb[1]=f2.y; xb[2]=f2.z; xb[3]=f2.w;
            xb[4]=f3.x; xb[5]=f3.y; xb[6]=f3.z; xb[7]=f3.w;
            int4 h0, l0, h1, l1;
            split8c(xa, h0, l0);
            split8c(xb, h1, l1);
            const int tsr = r >> 4, frr = r & 15;
            const int c8a = (t & 3) * 2, c8b = c8a + 1;
            const int oa = ((tsr * 2 + (c8a >> 2)) * 64 + (((c8a & 3) << 4) | frr)) * 8;
            const int ob = ((tsr * 2 + (c8b >> 2)) * 64 + (((c8b & 3) << 4) | frr)) * 8;
            *(int4*)&KFh[oa] = h0;  *(int4*)&KFl[oa] = l0;
            *(int4*)&KFh[ob] = h1;  *(int4*)&KFl[ob] = l1;
        }
        {
            const int r = t >> 2, c0 = (t & 3) * 16;
            const float* vp = vb + (size_t)(sb + r) * D_ + c0;
            float vv[16];
            float4 g0 = *(const float4*)(vp);
            float4 g1 = *(const float4*)(vp + 4);
            float4 g2 = *(const float4*)(vp + 8);
            float4 g3 = *(const float4*)(vp + 12);
            vv[0]=g0.x; vv[1]=g0.y; vv[2]=g0.z; vv[3]=g0.w;
            vv[4]=g1.x; vv[5]=g1.y; vv[6]=g1.z; vv[7]=g1.w;
            vv[8]=g2.x; vv[9]=g2.y; vv[10]=g2.z; vv[11]=g2.w;
            vv[12]=g3.x; vv[13]=g3.y; vv[14]=g3.z; vv[15]=g3.w;
            const int ks2 = r >> 5, kgp = (r & 31) >> 3, e = r & 7;
#pragma unroll
            for (int jj = 0; jj < 16; jj++) {
                int d = c0 + jj;
                int off = (((d >> 4) * 2 + ks2) * 64 + kgp * 16 + (d & 15)) * 8 + e;
                unsigned short h, l;
                split1(vv[jj], h, l);
                VTh[off] = h; VTl[off] = l;
            }
        }
        if (t < SUBT) mrw[t] = mask[(size_t)b * S_ + sb + t];
        __syncthreads();

        {
            const int ts = w;
#pragma unroll
            for (int at = 0; at < 3; at++) {
                f32x4 a4 = (f32x4){0.f, 0.f, 0.f, 0.f};
#pragma unroll
                for (int ks = 0; ks < 2; ks++) {
                    size_t oA = ((((size_t)bh * 3 + at) * 2 + ks) * 64 + lane) * 8;
                    short8v gh = *(const short8v*)&AG1h[oA];
                    short8v gl = *(const short8v*)&AG1l[oA];
                    short8v kh2 = *(const short8v*)&KFh[((ts * 2 + ks) * 64 + lane) * 8];
                    short8v kl2 = *(const short8v*)&KFl[((ts * 2 + ks) * 64 + lane) * 8];
                    a4 = __builtin_amdgcn_mfma_f32_16x16x32_bf16(gh, kh2, a4, 0, 0, 0);
                    a4 = __builtin_amdgcn_mfma_f32_16x16x32_bf16(gl, kh2, a4, 0, 0, 0);
                    a4 = __builtin_amdgcn_mfma_f32_16x16x32_bf16(gh, kl2, a4, 0, 0, 0);
                }
                *(f32x4*)&sc[ts * 16 + fr][at * 16 + kg * 4] = a4;
            }
        }
        for (int ut = w; ut < 7; ut += 4) {
            const int u = u0 + ut;
#pragma unroll
            for (int at = 0; at < 3; at++) {
                f32x4 a4 = (f32x4){0.f, 0.f, 0.f, 0.f};
#pragma unroll
                for (int ks = 0; ks < 2; ks++) {
                    size_t oA = ((((size_t)bh * 3 + at) * 2 + ks) * 64 + lane) * 8;
                    short8v gh = *(const short8v*)&AG1h[oA];
                    short8v gl = *(const short8v*)&AG1l[oA];
                    size_t oD = (((size_t)u * 2 + ks) * 64 + lane) * 8;
                    short8v dh = *(const short8v*)&D0h[oD];
                    short8v dl = *(const short8v*)&D0l[oD];
                    a4 = __builtin_amdgcn_mfma_f32_16x16x32_bf16(gh, dh, a4, 0, 0, 0);
                    a4 = __builtin_amdgcn_mfma_f32_16x16x32_bf16(gl, dh, a4, 0, 0, 0);
                    a4 = __builtin_amdgcn_mfma_f32_16x16x32_bf16(gh, dl, a4, 0, 0, 0);
                }
                *(f32x4*)&scp[ut * 16 + fr][at * 16 + kg * 4] = a4;
            }
        }
        __syncthreads();

        for (int i = t; i < SUBT * A_; i += 256) {
            int rr = i / 40, aa = i - rr * 40;
            sc[rr][aa] += scp[aa + 63 - rr][aa] + mrw[rr];
        }
        __syncthreads();
        if (t < 240) {
            int a = t % 40, r6 = t / 40;
            float mx = -INFINITY;
            for (int i = r6; i < SUBT; i += 6) mx = fmaxf(mx, sc[i][a]);
            pm6[r6][a] = mx;
        }
        __syncthreads();
        if (t < A_) {
            float lm = pm6[0][t];
#pragma unroll
            for (int r6 = 1; r6 < 6; r6++) lm = fmaxf(lm, pm6[r6][t]);
            float mnew = fmaxf(mrow[t], lm);
            resc[t] = __expf(mrow[t] - mnew);
            mrow[t] = mnew;
        }
        __syncthreads();
        for (int i = t; i < SUBT * A_; i += 256) {
            int rr = i / 40, aa = i - rr * 40;
            sc[rr][aa] = __expf(sc[rr][aa] - mrow[aa]);
        }
        __syncthreads();
        if (t < 240) {
            int a = t % 40, r6 = t / 40;
            float sm = 0.0f;
            for (int i = r6; i < SUBT; i += 6) sm += sc[i][a];
            pm6[r6][a] = sm;
        }
        __syncthreads();
        if (t < A_) {
            float ls = pm6[0][t] + pm6[1][t] + pm6[2][t] + pm6[3][t] + pm6[4][t] + pm6[5][t];
            lrow[t] = lrow[t] * resc[t] + ls;
        }
        __syncthreads();

        for (int g = t; g < 384; g += 256) {
            int pl = g & 63;
            int c = g >> 6;
            int at = c >> 1, ks2 = c & 1;
            int a = at * 16 + (pl & 15);
            int sl0 = ks2 * 32 + (pl >> 4) * 8;
            float xv[8];
#pragma unroll
            for (int e = 0; e < 8; e++)
                xv[e] = (a < A_) ? sc[sl0 + e][a] : 0.f;
            int4 hi, lo;
            split8c(xv, hi, lo);
            *(int4*)&KFh[g * 8] = hi;
            *(int4*)&KFl[g * 8] = lo;
        }
        __syncthreads();

        {
            const int dt = w;
#pragma unroll
            for (int at = 0; at < 3; at++) {
                f32x4 a4 = acc3[at];
#pragma unroll
                for (int p = 0; p < 4; p++) {
                    int a = at * 16 + kg * 4 + p;
                    float rs = (a < A_) ? resc[a] : 0.f;
                    a4[p] *= rs;
                }
#pragma unroll
                for (int ks2 = 0; ks2 < 2; ks2++) {
                    short8v ph = *(const short8v*)&KFh[((at * 2 + ks2) * 64 + lane) * 8];
                    short8v pll = *(const short8v*)&KFl[((at * 2 + ks2) * 64 + lane) * 8];
                    short8v vh = *(const short8v*)&VTh[((dt * 2 + ks2) * 64 + lane) * 8];
                    short8v vl = *(const short8v*)&VTl[((dt * 2 + ks2) * 64 + lane) * 8];
                    a4 = __builtin_amdgcn_mfma_f32_16x16x32_bf16(ph, vh, a4, 0, 0, 0);
                    a4 = __builtin_amdgcn_mfma_f32_16x16x32_bf16(pll, vh, a4, 0, 0, 0);
                    a4 = __builtin_amdgcn_mfma_f32_16x16x32_bf16(ph, vl, a4, 0, 0, 0);
                }
                acc3[at] = a4;
            }
        }
    }
    __syncthreads();

    {
        const int dt = w;
#pragma unroll
        for (int at = 0; at < 3; at++) {
#pragma unroll
            for (int p = 0; p < 4; p++) {
                int a = at * 16 + kg * 4 + p;
                if (a < A_)
                    Pacc[(((size_t)(bh * CH1 + q) * A_) + a) * D_ + dt * 16 + fr] = acc3[at][p];
            }
        }
    }
    if (t < A_) {
        Pm[(size_t)(bh * CH1 + q) * A_ + t] = mrow[t];
        Pl[(size_t)(bh * CH1 + q) * A_ + t] = lrow[t];
    }
}

// ---------------- stage 1 reduce ----------------
__global__ __launch_bounds__(256) void stage1_reduce(
    const float* __restrict__ Pacc, const float* __restrict__ Pm,
    const float* __restrict__ Pl, float* __restrict__ AgV)
{
    const int bh = blockIdx.x;
    const int t = threadIdx.x;
    __shared__ float F[CH1][A_], Linv[A_];
    if (t < A_) {
        float M = -INFINITY;
#pragma unroll
        for (int q = 0; q < CH1; q++) M = fmaxf(M, Pm[(size_t)(bh * CH1 + q) * A_ + t]);
        float L = 0.0f;
#pragma unroll
        for (int q = 0; q < CH1; q++) {
            float f = __expf(Pm[(size_t)(bh * CH1 + q) * A_ + t] - M);
            F[q][t] = f;
            L = fmaf(f, Pl[(size_t)(bh * CH1 + q) * A_ + t], L);
        }
        Linv[t] = 1.0f / L;
    }
    __syncthreads();
#pragma unroll
    for (int ii = 0; ii < 3; ii++) {
        int i = t + ii * 256;
        if (i < A_ * 16) {
            int a = i >> 4, d4 = i & 15;
            float4 s4 = make_float4(0.f, 0.f, 0.f, 0.f);
            for (int q = 0; q < CH1; q++) {
                float f = F[q][a];
                float4 p4 = *(const float4*)&Pacc[(((size_t)(bh * CH1 + q) * A_) + a) * D_ + d4 * 4];
                s4.x = fmaf(f, p4.x, s4.x);
                s4.y = fmaf(f, p4.y, s4.y);
                s4.z = fmaf(f, p4.z, s4.z);
                s4.w = fmaf(f, p4.w, s4.w);
            }
            float inv = Linv[a];
            s4.x *= inv; s4.y *= inv; s4.z *= inv; s4.w *= inv;
            *(float4*)&AgV[(size_t)bh * (A_ * D_) + a * D_ + d4 * 4] = s4;
        }
    }
}

// ------- stage 2 MFMA v5: no Q LDS, per-lane Q frags + reg prefetch, 3 blocks/CU ------
__global__ __launch_bounds__(256, 3) void stage2_mfma(
    const float* __restrict__ Qg,
    const unsigned short* __restrict__ AGFh, const unsigned short* __restrict__ AGFl,
    const unsigned short* __restrict__ DFh,  const unsigned short* __restrict__ DFl,
    const unsigned short* __restrict__ AVFh, const unsigned short* __restrict__ AVFl,
    float* __restrict__ Out)
{
    const int sb8 = blockIdx.x;      // 0..7 (4 chunks of 64 s)
    const int bh  = blockIdx.y;      // 0..191
    const int b = bh / H_, h = bh % H_;

    __shared__ float scm[64][52];
    __shared__ float scp[64][68];
    __shared__ unsigned short PAh[64][72], PAl[64][72];

    const int t = threadIdx.x;
    const int lane = t & 63, ts = t >> 6;
    const int fr = lane & 15, kg = lane >> 4;

    // hoisted AG fragments (bh-only, loop-invariant)
    short8v agh[3][2], agl[3][2];
#pragma unroll
    for (int at = 0; at < 3; at++)
#pragma unroll
        for (int ks = 0; ks < 2; ks++) {
            size_t o = ((((size_t)bh * 3 + at) * 2 + ks) * 64 + lane) * 8;
            agh[at][ks] = *(const short8v*)&AGFh[o];
            agl[at][ks] = *(const short8v*)&AGFl[o];
        }

    // per-lane Q fragment base (row = s0 + ts*16 + fr; cols ks*32 + kg*8)
    const float* qlane = Qg + ((size_t)bh * S_ + sb8 * 256 + ts * 16 + fr) * D_ + kg * 8;

    // prologue: chunk 0 Q into regs
    float4 f0 = *(const float4*)(qlane);
    float4 f1 = *(const float4*)(qlane + 4);
    float4 f2 = *(const float4*)(qlane + 32);
    float4 f3 = *(const float4*)(qlane + 36);

    for (int c = 0; c < 4; c++) {
        const int s0 = sb8 * 256 + c * 64;
        const int base_u = (s0 >> 4) + 125;

        // convert current Q regs -> fragments
        float xa[8] = {f0.x, f0.y, f0.z, f0.w, f1.x, f1.y, f1.z, f1.w};
        float xb[8] = {f2.x, f2.y, f2.z, f2.w, f3.x, f3.y, f3.z, f3.w};
        int4 h0, l0, h1, l1;
        split8c(xa, h0, l0);
        split8c(xb, h1, l1);
        short8v qh[2], ql[2];
        qh[0] = __builtin_bit_cast(short8v, h0);  ql[0] = __builtin_bit_cast(short8v, l0);
        qh[1] = __builtin_bit_cast(short8v, h1);  ql[1] = __builtin_bit_cast(short8v, l1);

        // prefetch next chunk's Q (in flight across scores phase)
        if (c < 3) {
            const float* np = qlane + (size_t)(c + 1) * 64 * D_;
            f0 = *(const float4*)(np);
            f1 = *(const float4*)(np + 4);
            f2 = *(const float4*)(np + 32);
            f3 = *(const float4*)(np + 36);
        }

        // ---- scores: AG (hoisted frags) ----
#pragma unroll
        for (int at = 0; at < 3; at++) {
            f32x4 acc = (f32x4){0.f, 0.f, 0.f, 0.f};
#pragma unroll
            for (int ks = 0; ks < 2; ks++) {
                acc = __builtin_amdgcn_mfma_f32_16x16x32_bf16(agh[at][ks], qh[ks], acc, 0, 0, 0);
                acc = __builtin_amdgcn_mfma_f32_16x16x32_bf16(agl[at][ks], qh[ks], acc, 0, 0, 0);
                acc = __builtin_amdgcn_mfma_f32_16x16x32_bf16(agh[at][ks], ql[ks], acc, 0, 0, 0);
            }
            *(f32x4*)&scm[ts * 16 + fr][at * 16 + kg * 4] = acc;
        }
        // ---- scores: PE band ----
#pragma unroll
        for (int o4 = 0; o4 < 4; o4++) {
            f32x4 acc = (f32x4){0.f, 0.f, 0.f, 0.f};
            const int u = base_u + ts + o4;
#pragma unroll
            for (int ks = 0; ks < 2; ks++) {
                size_t o = (((size_t)u * 2 + ks) * 64 + lane) * 8;
                short8v chv = *(const short8v*)&DFh[o];
                short8v clv = *(const short8v*)&DFl[o];
                acc = __builtin_amdgcn_mfma_f32_16x16x32_bf16(chv, qh[ks], acc, 0, 0, 0);
                acc = __builtin_amdgcn_mfma_f32_16x16x32_bf16(clv, qh[ks], acc, 0, 0, 0);
                acc = __builtin_amdgcn_mfma_f32_16x16x32_bf16(chv, ql[ks], acc, 0, 0, 0);
            }
            *(f32x4*)&scp[ts * 16 + fr][o4 * 16 + kg * 4] = acc;
        }
        __syncthreads();   // scores ready (also: prior chunk's PA reads complete)

        // ---- softmax over a (4 threads per s-row) ----
        {
            const int rr = t >> 2, dq = t & 3;
            const int base = (rr & 15) + 39;
            float val[10];
#pragma unroll
            for (int i = 0; i < 10; i++) {
                int a = dq * 10 + i;
                val[i] = scm[rr][a] + scp[rr][base - a];
            }
            float mx = -INFINITY;
#pragma unroll
            for (int i = 0; i < 10; i++) mx = fmaxf(mx, val[i]);
            mx = fmaxf(mx, __shfl_xor(mx, 1));
            mx = fmaxf(mx, __shfl_xor(mx, 2));
            float sum = 0.f;
#pragma unroll
            for (int i = 0; i < 10; i++) { val[i] = __expf(val[i] - mx); sum += val[i]; }
            sum += __shfl_xor(sum, 1);
            sum += __shfl_xor(sum, 2);
            float inv = 1.0f / sum;
            unsigned* ph = (unsigned*)&PAh[rr][0];
            unsigned* pl = (unsigned*)&PAl[rr][0];
#pragma unroll
            for (int i = 0; i < 5; i++) {
                unsigned short hh0, ll0, hh1, ll1;
                split1(val[2 * i] * inv, hh0, ll0);
                split1(val[2 * i + 1] * inv, hh1, ll1);
                ph[dq * 5 + i] = (unsigned)hh0 | ((unsigned)hh1 << 16);
                pl[dq * 5 + i] = (unsigned)ll0 | ((unsigned)ll1 << 16);
            }
#pragma unroll
            for (int i = 0; i < 3; i++) { ph[20 + dq * 3 + i] = 0u; pl[20 + dq * 3 + i] = 0u; }
        }
        __syncthreads();   // PA ready

        // ---- PV + store ----
        short8v ph8[2], pl8[2];
#pragma unroll
        for (int ks = 0; ks < 2; ks++) {
            ph8[ks] = *(const short8v*)&PAh[ts * 16 + fr][ks * 32 + kg * 8];
            pl8[ks] = *(const short8v*)&PAl[ts * 16 + fr][ks * 32 + kg * 8];
        }
#pragma unroll
        for (int nt = 0; nt < 4; nt++) {
            f32x4 acc = (f32x4){0.f, 0.f, 0.f, 0.f};
#pragma unroll
            for (int ks = 0; ks < 2; ks++) {
                size_t o = ((((size_t)bh * 4 + nt) * 2 + ks) * 64 + lane) * 8;
                short8v vh = *(const short8v*)&AVFh[o];
                short8v vl = *(const short8v*)&AVFl[o];
                acc = __builtin_amdgcn_mfma_f32_16x16x32_bf16(ph8[ks], vh, acc, 0, 0, 0);
                acc = __builtin_amdgcn_mfma_f32_16x16x32_bf16(pl8[ks], vh, acc, 0, 0, 0);
                acc = __builtin_amdgcn_mfma_f32_16x16x32_bf16(ph8[ks], vl, acc, 0, 0, 0);
            }
            const int d = nt * 16 + fr;
            float* op = Out + ((size_t)b * S_ + s0 + ts * 16 + kg * 4) * HID + h * D_ + d;
#pragma unroll
            for (int rr = 0; rr < 4; rr++)
                op[(size_t)rr * HID] = acc[rr];
        }
        // no barrier needed here: next chunk's scm/scp & PA writes are after its scores barrier
    }
}

extern "C" void kernel_launch(void* const* d_in, const int* in_sizes, int n_in,
                              void* d_out, int out_size, void* d_ws, size_t ws_size,
                              hipStream_t stream) {
    const float* hs   = (const float*)d_in[0];
    const float* mask = (const float*)d_in[1];
    const float* Wq   = (const float*)d_in[2];
    const float* bq   = (const float*)d_in[3];
    const float* Wk   = (const float*)d_in[4];
    const float* bk   = (const float*)d_in[5];
    const float* Wv   = (const float*)d_in[6];
    const float* bv   = (const float*)d_in[7];
    const float* dist = (const float*)d_in[8];
    float* out = (float*)d_out;

    float* ws = (float*)d_ws;
    const size_t QKV = (size_t)B_ * H_ * S_ * D_;
    const size_t AG  = (size_t)B_ * H_ * A_ * D_;
    float* Q     = ws;
    float* K     = ws + QKV;
    float* V     = ws + 2 * QKV;
    float* Agent = ws + 3 * QKV;     // unused (kept for layout stability)
    float* AgV   = Agent + AG;
    float* Pacc  = AgV + AG;
    float* Pm    = Pacc + (size_t)B_ * H_ * CH1 * A_ * D_;
    float* Pl    = Pm + (size_t)B_ * H_ * CH1 * A_;
    unsigned short* Wth = (unsigned short*)(Pl + (size_t)B_ * H_ * CH1 * A_);
    unsigned short* Wtl = Wth + (size_t)3 * HID * HID;
    unsigned short* DFh = Wtl + (size_t)3 * HID * HID;
    unsigned short* DFl = DFh + (size_t)262144;
    unsigned short* AGFh = DFl + (size_t)262144;
    unsigned short* AGFl = AGFh + (size_t)589824;
    unsigned short* AVFh = AGFl + (size_t)589824;
    unsigned short* AVFl = AVFh + (size_t)786432;
    unsigned short* AG1h = AVFl + (size_t)786432;
    unsigned short* AG1l = AG1h + (size_t)589824;
    unsigned short* D0h  = AG1l + (size_t)589824;
    unsigned short* D0l  = D0h + (size_t)134144;
    // total ws ~340 MB (within known-good <=393 MB budget)

    preconvert<<<WT_BLKS + DF_BLKS + D0_BLKS, 256, 0, stream>>>(
        Wq, Wk, Wv, dist, Wth, Wtl, DFh, DFl, D0h, D0l);
    qkv_z<<<2304, 512, 0, stream>>>(hs, Wth, Wtl, bq, bk, bv, Q, K, V);
    agpool_frag<<<B_ * H_, 256, 0, stream>>>(Q, AGFh, AGFl, AG1h, AG1l);
    dim3 g1(CH1, B_ * H_);
    stage1_mfma<<<g1, 256, 0, stream>>>(K, V, AG1h, AG1l, D0h, D0l, mask, Pacc, Pm, Pl);
    stage1_reduce<<<B_ * H_, 256, 0, stream>>>(Pacc, Pm, Pl, AgV);
    avt_frag<<<(192 * 4 * 2 * 64 + 255) / 256, 256, 0, stream>>>(AgV, AVFh, AVFl);
    dim3 g2(8, B_ * H_);
    stage2_mfma<<<g2, 256, 0, stream>>>(Q, AGFh, AGFl, DFh, DFl, AVFh, AVFl, out);
}

// Round 17
// 558.091 us; speedup vs baseline: 1.0442x; 1.0442x over previous
//
#include <hip/hip_runtime.h>
#include <math.h>

#define B_ 16
#define S_ 2048
#define H_ 12
#define D_ 64
#define HID 768
#define A_ 40
#define SCALE_ 0.125f
#define CH1 8          // stage1 s-chunks per (b,h)
#define SUBT 64        // s per subtile
#define NSUB 4         // subtiles per block (256 s per block)

typedef __attribute__((ext_vector_type(8))) short short8v;    // 8 bf16 (4 VGPR)
typedef __attribute__((ext_vector_type(4))) float f32x4;
typedef __attribute__((ext_vector_type(16))) float f32x16;    // 32x32 MFMA C/D

__device__ __forceinline__ unsigned f2bf_bits(float x) {
    unsigned u = __float_as_uint(x);
    return (u + 0x7FFFu + ((u >> 16) & 1u)) >> 16;   // RTNE
}

__device__ __forceinline__ void split1(float v, unsigned short& h, unsigned short& l) {
    __bf16 bh = (__bf16)v;
    float hf = (float)bh;
    __bf16 bl = (__bf16)(v - hf);
    h = __builtin_bit_cast(unsigned short, bh);
    l = __builtin_bit_cast(unsigned short, bl);
}

// split 8 fp32 -> hi/lo bf16 via native __bf16 casts (RTNE)
__device__ __forceinline__ void split8c(const float* x, int4& hi, int4& lo) {
    unsigned h[8], l[8];
#pragma unroll
    for (int i = 0; i < 8; i++) {
        __bf16 bh = (__bf16)x[i];
        float hf = (float)bh;
        __bf16 bl = (__bf16)(x[i] - hf);
        h[i] = (unsigned)__builtin_bit_cast(unsigned short, bh);
        l[i] = (unsigned)__builtin_bit_cast(unsigned short, bl);
    }
    hi = make_int4((int)(h[0] | (h[1] << 16)), (int)(h[2] | (h[3] << 16)),
                   (int)(h[4] | (h[5] << 16)), (int)(h[6] | (h[7] << 16)));
    lo = make_int4((int)(l[0] | (l[1] << 16)), (int)(l[2] | (l[3] << 16)),
                   (int)(l[4] | (l[5] << 16)), (int)(l[6] | (l[7] << 16)));
}

// ------- merged input preconvert: W transpose/split + dist frag tables ----------
#define WT_BLKS 1728   // 3*192*768 / 256
#define DF_BLKS 128    // 256*2*64 / 256
#define D0_BLKS 66     // ceil(131*2*64 / 256)
__global__ __launch_bounds__(256) void preconvert(
    const float* __restrict__ Wq, const float* __restrict__ Wk, const float* __restrict__ Wv,
    const float* __restrict__ dist,
    unsigned short* __restrict__ Wth, unsigned short* __restrict__ Wtl,
    unsigned short* __restrict__ DFh, unsigned short* __restrict__ DFl,
    unsigned short* __restrict__ D0h, unsigned short* __restrict__ D0l)
{
    const int bx = blockIdx.x;
    const int t = threadIdx.x;
    if (bx < WT_BLKS) {
        int idx = bx * 256 + t;
        if (idx >= 3 * 192 * 768) return;
        int n  = idx % 768;
        int kc = (idx / 768) % 192;
        int z  = idx / (768 * 192);
        const float* W = (z == 0) ? Wq : (z == 1) ? Wk : Wv;
        unsigned short h4[4], l4[4];
#pragma unroll
        for (int i = 0; i < 4; i++) {
            float x = W[(size_t)(4 * kc + i) * HID + n];
            unsigned hb = f2bf_bits(x);
            float hf = __uint_as_float(hb << 16);
            h4[i] = (unsigned short)hb;
            l4[i] = (unsigned short)f2bf_bits(x - hf);
        }
        size_t o = ((size_t)z * HID + n) * HID + 4 * kc;
        *(ushort4*)&Wth[o] = make_ushort4(h4[0], h4[1], h4[2], h4[3]);
        *(ushort4*)&Wtl[o] = make_ushort4(l4[0], l4[1], l4[2], l4[3]);
    } else if (bx < WT_BLKS + DF_BLKS) {
        int g = (bx - WT_BLKS) * 256 + t;
        int lane = g & 63;
        int ks = (g >> 6) & 1;
        int u  = g >> 7;
        int row = 8 + u * 16 + (lane & 15);
        int col = ks * 32 + ((lane >> 4) << 3);
        float xv[8];
#pragma unroll
        for (int j = 0; j < 8; j++)
            xv[j] = (row < 4095) ? dist[(size_t)row * D_ + col + j] : 0.f;
        int4 hi, lo;
        split8c(xv, hi, lo);
        *(int4*)&DFh[(size_t)g * 8] = hi;
        *(int4*)&DFl[(size_t)g * 8] = lo;
    } else {
        int g = (bx - WT_BLKS - DF_BLKS) * 256 + t;
        if (g >= 131 * 2 * 64) return;
        int lane = g & 63;
        int ks = (g >> 6) & 1;
        int u  = g >> 7;
        int row = u * 16 + (lane & 15);
        int col = ks * 32 + ((lane >> 4) << 3);
        float xv[8];
#pragma unroll
        for (int j = 0; j < 8; j++) xv[j] = dist[(size_t)row * D_ + col + j];
        int4 hi, lo;
        split8c(xv, hi, lo);
        *(int4*)&D0h[(size_t)g * 8] = hi;
        *(int4*)&D0l[(size_t)g * 8] = lo;
    }
}

// ------- AgV^T -> fragment-major: [bh][nt<4][ks][lane][8] rows=d, cols=a ----------
__global__ void avt_frag(const float* __restrict__ AgV,
                         unsigned short* __restrict__ Vh, unsigned short* __restrict__ Vl)
{
    int g = blockIdx.x * 256 + threadIdx.x;   // 192*4*2*64
    if (g >= 192 * 4 * 2 * 64) return;
    int lane = g & 63;
    int r = g >> 6;
    int ks = r & 1; r >>= 1;
    int nt = r & 3;
    int bh = r >> 2;
    int d = nt * 16 + (lane & 15);
    int a0 = ks * 32 + ((lane >> 4) << 3);
    float xv[8];
#pragma unroll
    for (int j = 0; j < 8; j++) {
        int a = a0 + j;
        xv[j] = (a < A_) ? AgV[((size_t)bh * A_ + a) * D_ + d] : 0.f;
    }
    int4 hi, lo;
    split8c(xv, hi, lo);
    *(int4*)&Vh[(size_t)g * 8] = hi;
    *(int4*)&Vl[(size_t)g * 8] = lo;
}

// ---------------- QKV: bf16x3 MFMA GEMM (32x32x16), 128x256 tile, XCD-swizzled ----------
__global__ __launch_bounds__(512, 2) void qkv_z(
    const float* __restrict__ X,
    const unsigned short* __restrict__ Wth, const unsigned short* __restrict__ Wtl,
    const float* __restrict__ bq, const float* __restrict__ bk, const float* __restrict__ bv,
    float* __restrict__ Q, float* __restrict__ K, float* __restrict__ V)
{
    const int L   = blockIdx.x;
    const int k8  = L & 7, sl_ = L >> 3;
    const int mt  = k8 * 32 + sl_ / 9;
    const int sub = sl_ % 9;
    const int nt  = sub % 3, zz = sub / 3;
    const int m0 = mt * 128, n0 = nt * 256;

    const float* __restrict__ bias = (zz == 0) ? bq : (zz == 1) ? bk : bv;
    float* __restrict__ Out        = (zz == 0) ? Q  : (zz == 1) ? K  : V;
    const unsigned short* __restrict__ Bhg = Wth + (size_t)zz * HID * HID;
    const unsigned short* __restrict__ Blg = Wtl + (size_t)zz * HID * HID;

    __shared__ unsigned short Ah[128][40];
    __shared__ unsigned short Al[128][40];
    __shared__ unsigned short Bh[256][40];
    __shared__ unsigned short Bl[256][40];

    const int t = threadIdx.x;
    const int lane = t & 63, w = t >> 6;
    const int wm = (w & 1) * 64, wn = (w >> 1) * 64;
    const int r32 = lane & 31, kh = lane >> 5;

    const int sr = t >> 2, sca = (t & 3) * 8;
    const int sb = t >> 1, scb = (t & 1) * 16;

    f32x16 acc[2][2];
#pragma unroll
    for (int i = 0; i < 2; i++)
#pragma unroll
        for (int j = 0; j < 2; j++)
#pragma unroll
            for (int p = 0; p < 16; p++) acc[i][j][p] = 0.f;

    for (int k0 = 0; k0 < HID; k0 += 32) {
        float xv[8];
        const float* xp = X + (size_t)(m0 + sr) * HID + k0 + sca;
        float4 f0 = *(const float4*)xp;
        float4 f1 = *(const float4*)(xp + 4);
        xv[0] = f0.x; xv[1] = f0.y; xv[2] = f0.z; xv[3] = f0.w;
        xv[4] = f1.x; xv[5] = f1.y; xv[6] = f1.z; xv[7] = f1.w;
        int4 ah, al;
        split8c(xv, ah, al);
        size_t bo = (size_t)(n0 + sb) * HID + k0 + scb;
        int4 bh0 = *(const int4*)&Bhg[bo];
        int4 bh1 = *(const int4*)&Bhg[bo + 8];
        int4 bl0 = *(const int4*)&Blg[bo];
        int4 bl1 = *(const int4*)&Blg[bo + 8];

        __syncthreads();
        *(int4*)&Ah[sr][sca] = ah;
        *(int4*)&Al[sr][sca] = al;
        *(int4*)&Bh[sb][scb]     = bh0;  *(int4*)&Bh[sb][scb + 8] = bh1;
        *(int4*)&Bl[sb][scb]     = bl0;  *(int4*)&Bl[sb][scb + 8] = bl1;
        __syncthreads();

#pragma unroll
        for (int ks = 0; ks < 2; ks++) {
            const int ko = ks * 16 + kh * 8;
            short8v a_h[2], a_l[2], b_h[2], b_l[2];
#pragma unroll
            for (int i = 0; i < 2; i++) {
                a_h[i] = *(const short8v*)&Ah[wm + i * 32 + r32][ko];
                a_l[i] = *(const short8v*)&Al[wm + i * 32 + r32][ko];
                b_h[i] = *(const short8v*)&Bh[wn + i * 32 + r32][ko];
                b_l[i] = *(const short8v*)&Bl[wn + i * 32 + r32][ko];
            }
#pragma unroll
            for (int i = 0; i < 2; i++)
#pragma unroll
                for (int j = 0; j < 2; j++) {
                    acc[i][j] = __builtin_amdgcn_mfma_f32_32x32x16_bf16(a_h[i], b_h[j], acc[i][j], 0, 0, 0);
                    acc[i][j] = __builtin_amdgcn_mfma_f32_32x32x16_bf16(a_l[i], b_h[j], acc[i][j], 0, 0, 0);
                    acc[i][j] = __builtin_amdgcn_mfma_f32_32x32x16_bf16(a_h[i], b_l[j], acc[i][j], 0, 0, 0);
                }
        }
    }

    const float scl = (zz == 1) ? SCALE_ : 1.0f;
#pragma unroll
    for (int j = 0; j < 2; j++) {
        int n = n0 + wn + j * 32 + r32;
        float bj = bias[n];
        int h = n >> 6, d = n & 63;
#pragma unroll
        for (int i = 0; i < 2; i++) {
#pragma unroll
            for (int p = 0; p < 16; p++) {
                int m = m0 + wm + i * 32 + (p & 3) + 8 * (p >> 2) + 4 * kh;
                int b = m >> 11, s = m & 2047;
                Out[(((size_t)b * H_ + h) * S_ + s) * D_ + d] = (acc[i][j][p] + bj) * scl;
            }
        }
    }
}

// ------- agent pooling + AG fragment tables ----------
__global__ __launch_bounds__(256) void agpool_frag(
    const float* __restrict__ Q,
    unsigned short* __restrict__ AGFh, unsigned short* __restrict__ AGFl,
    unsigned short* __restrict__ AG1h, unsigned short* __restrict__ AG1l)
{
    const int bh = blockIdx.x;
    const int t = threadIdx.x;
    __shared__ float ag[A_][D_];
    const float* base = Q + (size_t)bh * (S_ * D_);
    for (int i = t; i < A_ * D_; i += 256) {
        int d = i & 63, a = i >> 6;
        float src = ((float)a + 0.5f) * (2048.0f / 40.0f) - 0.5f;
        src = fminf(fmaxf(src, 0.0f), 2047.0f);
        int lo = (int)floorf(src);
        int hi = min(lo + 1, S_ - 1);
        float w = src - (float)lo;
        ag[a][d] = base[lo * D_ + d] * (1.0f - w) + base[hi * D_ + d] * w;
    }
    __syncthreads();
    for (int g = t; g < 384; g += 256) {
        int lane = g & 63;
        int ks = (g >> 6) & 1;
        int at = g >> 7;
        int a = at * 16 + (lane & 15);
        int col = ks * 32 + ((lane >> 4) << 3);
        float xs[8], x1[8];
#pragma unroll
        for (int j = 0; j < 8; j++) {
            float v = (a < A_) ? ag[a][col + j] : 0.f;
            x1[j] = v; xs[j] = v * SCALE_;
        }
        int4 h1, l1, h2, l2;
        split8c(xs, h1, l1);
        split8c(x1, h2, l2);
        size_t o = ((((size_t)bh * 3 + at) * 2 + ks) * 64 + lane) * 8;
        *(int4*)&AGFh[o] = h1;  *(int4*)&AGFl[o] = l1;
        *(int4*)&AG1h[o] = h2;  *(int4*)&AG1l[o] = l2;
    }
}

// ---------------- stage 1 MFMA (round-13 proven) ----------------
__global__ __launch_bounds__(256, 2) void stage1_mfma(
    const float* __restrict__ Kl, const float* __restrict__ Vl,
    const unsigned short* __restrict__ AG1h, const unsigned short* __restrict__ AG1l,
    const unsigned short* __restrict__ D0h,  const unsigned short* __restrict__ D0l,
    const float* __restrict__ mask,
    float* __restrict__ Pacc, float* __restrict__ Pm, float* __restrict__ Pl)
{
    const int q  = blockIdx.x;
    const int bh = blockIdx.y;
    const int b  = bh / H_;
    const int s0 = q * (NSUB * SUBT);
    const float* __restrict__ kb = Kl + (size_t)bh * (S_ * D_);
    const float* __restrict__ vb = Vl + (size_t)bh * (S_ * D_);

    __shared__ unsigned short KFh[4096], KFl[4096];
    __shared__ unsigned short VTh[4096], VTl[4096];
    __shared__ float sc[SUBT][52];
    __shared__ float scp[112][52];
    __shared__ float pm6[6][A_];
    __shared__ float mrow[A_], lrow[A_], resc[A_], mrw[SUBT];

    const int t = threadIdx.x;
    const int lane = t & 63, w = t >> 6;
    const int fr = lane & 15, kg = lane >> 4;

    if (t < A_) { mrow[t] = -INFINITY; lrow[t] = 0.0f; }

    f32x4 acc3[3];
#pragma unroll
    for (int at = 0; at < 3; at++) acc3[at] = (f32x4){0.f, 0.f, 0.f, 0.f};

    for (int st = 0; st < NSUB; st++) {
        const int sb = s0 + st * SUBT;
        const int u0 = (1984 - sb) >> 4;

        __syncthreads();

        {
            const int r = t >> 2, c0 = (t & 3) * 16;
            const float* kp = kb + (size_t)(sb + r) * D_ + c0;
            float xa[8], xb[8];
            float4 f0 = *(const float4*)(kp);
            float4 f1 = *(const float4*)(kp + 4);
            float4 f2 = *(const float4*)(kp + 8);
            float4 f3 = *(const float4*)(kp + 12);
            xa[0]=f0.x; xa[1]=f0.y; xa[2]=f0.z; xa[3]=f0.w;
            xa[4]=f1.x; xa[5]=f1.y; xa[6]=f1.z; xa[7]=f1.w;
            xb[0]=f2.x; xb[1]=f2.y; xb[2]=f2.z; xb[3]=f2.w;
            xb[4]=f3.x; xb[5]=f3.y; xb[6]=f3.z; xb[7]=f3.w;
            int4 h0, l0, h1, l1;
            split8c(xa, h0, l0);
            split8c(xb, h1, l1);
            const int tsr = r >> 4, frr = r & 15;
            const int c8a = (t & 3) * 2, c8b = c8a + 1;
            const int oa = ((tsr * 2 + (c8a >> 2)) * 64 + (((c8a & 3) << 4) | frr)) * 8;
            const int ob = ((tsr * 2 + (c8b >> 2)) * 64 + (((c8b & 3) << 4) | frr)) * 8;
            *(int4*)&KFh[oa] = h0;  *(int4*)&KFl[oa] = l0;
            *(int4*)&KFh[ob] = h1;  *(int4*)&KFl[ob] = l1;
        }
        {
            const int r = t >> 2, c0 = (t & 3) * 16;
            const float* vp = vb + (size_t)(sb + r) * D_ + c0;
            float vv[16];
            float4 g0 = *(const float4*)(vp);
            float4 g1 = *(const float4*)(vp + 4);
            float4 g2 = *(const float4*)(vp + 8);
            float4 g3 = *(const float4*)(vp + 12);
            vv[0]=g0.x; vv[1]=g0.y; vv[2]=g0.z; vv[3]=g0.w;
            vv[4]=g1.x; vv[5]=g1.y; vv[6]=g1.z; vv[7]=g1.w;
            vv[8]=g2.x; vv[9]=g2.y; vv[10]=g2.z; vv[11]=g2.w;
            vv[12]=g3.x; vv[13]=g3.y; vv[14]=g3.z; vv[15]=g3.w;
            const int ks2 = r >> 5, kgp = (r & 31) >> 3, e = r & 7;
#pragma unroll
            for (int jj = 0; jj < 16; jj++) {
                int d = c0 + jj;
                int off = (((d >> 4) * 2 + ks2) * 64 + kgp * 16 + (d & 15)) * 8 + e;
                unsigned short h, l;
                split1(vv[jj], h, l);
                VTh[off] = h; VTl[off] = l;
            }
        }
        if (t < SUBT) mrw[t] = mask[(size_t)b * S_ + sb + t];
        __syncthreads();

        {
            const int ts = w;
#pragma unroll
            for (int at = 0; at < 3; at++) {
                f32x4 a4 = (f32x4){0.f, 0.f, 0.f, 0.f};
#pragma unroll
                for (int ks = 0; ks < 2; ks++) {
                    size_t oA = ((((size_t)bh * 3 + at) * 2 + ks) * 64 + lane) * 8;
                    short8v gh = *(const short8v*)&AG1h[oA];
                    short8v gl = *(const short8v*)&AG1l[oA];
                    short8v kh2 = *(const short8v*)&KFh[((ts * 2 + ks) * 64 + lane) * 8];
                    short8v kl2 = *(const short8v*)&KFl[((ts * 2 + ks) * 64 + lane) * 8];
                    a4 = __builtin_amdgcn_mfma_f32_16x16x32_bf16(gh, kh2, a4, 0, 0, 0);
                    a4 = __builtin_amdgcn_mfma_f32_16x16x32_bf16(gl, kh2, a4, 0, 0, 0);
                    a4 = __builtin_amdgcn_mfma_f32_16x16x32_bf16(gh, kl2, a4, 0, 0, 0);
                }
                *(f32x4*)&sc[ts * 16 + fr][at * 16 + kg * 4] = a4;
            }
        }
        for (int ut = w; ut < 7; ut += 4) {
            const int u = u0 + ut;
#pragma unroll
            for (int at = 0; at < 3; at++) {
                f32x4 a4 = (f32x4){0.f, 0.f, 0.f, 0.f};
#pragma unroll
                for (int ks = 0; ks < 2; ks++) {
                    size_t oA = ((((size_t)bh * 3 + at) * 2 + ks) * 64 + lane) * 8;
                    short8v gh = *(const short8v*)&AG1h[oA];
                    short8v gl = *(const short8v*)&AG1l[oA];
                    size_t oD = (((size_t)u * 2 + ks) * 64 + lane) * 8;
                    short8v dh = *(const short8v*)&D0h[oD];
                    short8v dl = *(const short8v*)&D0l[oD];
                    a4 = __builtin_amdgcn_mfma_f32_16x16x32_bf16(gh, dh, a4, 0, 0, 0);
                    a4 = __builtin_amdgcn_mfma_f32_16x16x32_bf16(gl, dh, a4, 0, 0, 0);
                    a4 = __builtin_amdgcn_mfma_f32_16x16x32_bf16(gh, dl, a4, 0, 0, 0);
                }
                *(f32x4*)&scp[ut * 16 + fr][at * 16 + kg * 4] = a4;
            }
        }
        __syncthreads();

        for (int i = t; i < SUBT * A_; i += 256) {
            int rr = i / 40, aa = i - rr * 40;
            sc[rr][aa] += scp[aa + 63 - rr][aa] + mrw[rr];
        }
        __syncthreads();
        if (t < 240) {
            int a = t % 40, r6 = t / 40;
            float mx = -INFINITY;
            for (int i = r6; i < SUBT; i += 6) mx = fmaxf(mx, sc[i][a]);
            pm6[r6][a] = mx;
        }
        __syncthreads();
        if (t < A_) {
            float lm = pm6[0][t];
#pragma unroll
            for (int r6 = 1; r6 < 6; r6++) lm = fmaxf(lm, pm6[r6][t]);
            float mnew = fmaxf(mrow[t], lm);
            resc[t] = __expf(mrow[t] - mnew);
            mrow[t] = mnew;
        }
        __syncthreads();
        for (int i = t; i < SUBT * A_; i += 256) {
            int rr = i / 40, aa = i - rr * 40;
            sc[rr][aa] = __expf(sc[rr][aa] - mrow[aa]);
        }
        __syncthreads();
        if (t < 240) {
            int a = t % 40, r6 = t / 40;
            float sm = 0.0f;
            for (int i = r6; i < SUBT; i += 6) sm += sc[i][a];
            pm6[r6][a] = sm;
        }
        __syncthreads();
        if (t < A_) {
            float ls = pm6[0][t] + pm6[1][t] + pm6[2][t] + pm6[3][t] + pm6[4][t] + pm6[5][t];
            lrow[t] = lrow[t] * resc[t] + ls;
        }
        __syncthreads();

        for (int g = t; g < 384; g += 256) {
            int pl = g & 63;
            int c = g >> 6;
            int at = c >> 1, ks2 = c & 1;
            int a = at * 16 + (pl & 15);
            int sl0 = ks2 * 32 + (pl >> 4) * 8;
            float xv[8];
#pragma unroll
            for (int e = 0; e < 8; e++)
                xv[e] = (a < A_) ? sc[sl0 + e][a] : 0.f;
            int4 hi, lo;
            split8c(xv, hi, lo);
            *(int4*)&KFh[g * 8] = hi;
            *(int4*)&KFl[g * 8] = lo;
        }
        __syncthreads();

        {
            const int dt = w;
#pragma unroll
            for (int at = 0; at < 3; at++) {
                f32x4 a4 = acc3[at];
#pragma unroll
                for (int p = 0; p < 4; p++) {
                    int a = at * 16 + kg * 4 + p;
                    float rs = (a < A_) ? resc[a] : 0.f;
                    a4[p] *= rs;
                }
#pragma unroll
                for (int ks2 = 0; ks2 < 2; ks2++) {
                    short8v ph = *(const short8v*)&KFh[((at * 2 + ks2) * 64 + lane) * 8];
                    short8v pll = *(const short8v*)&KFl[((at * 2 + ks2) * 64 + lane) * 8];
                    short8v vh = *(const short8v*)&VTh[((dt * 2 + ks2) * 64 + lane) * 8];
                    short8v vl = *(const short8v*)&VTl[((dt * 2 + ks2) * 64 + lane) * 8];
                    a4 = __builtin_amdgcn_mfma_f32_16x16x32_bf16(ph, vh, a4, 0, 0, 0);
                    a4 = __builtin_amdgcn_mfma_f32_16x16x32_bf16(pll, vh, a4, 0, 0, 0);
                    a4 = __builtin_amdgcn_mfma_f32_16x16x32_bf16(ph, vl, a4, 0, 0, 0);
                }
                acc3[at] = a4;
            }
        }
    }
    __syncthreads();

    {
        const int dt = w;
#pragma unroll
        for (int at = 0; at < 3; at++) {
#pragma unroll
            for (int p = 0; p < 4; p++) {
                int a = at * 16 + kg * 4 + p;
                if (a < A_)
                    Pacc[(((size_t)(bh * CH1 + q) * A_) + a) * D_ + dt * 16 + fr] = acc3[at][p];
            }
        }
    }
    if (t < A_) {
        Pm[(size_t)(bh * CH1 + q) * A_ + t] = mrow[t];
        Pl[(size_t)(bh * CH1 + q) * A_ + t] = lrow[t];
    }
}

// ---------------- stage 1 reduce ----------------
__global__ __launch_bounds__(256) void stage1_reduce(
    const float* __restrict__ Pacc, const float* __restrict__ Pm,
    const float* __restrict__ Pl, float* __restrict__ AgV)
{
    const int bh = blockIdx.x;
    const int t = threadIdx.x;
    __shared__ float F[CH1][A_], Linv[A_];
    if (t < A_) {
        float M = -INFINITY;
#pragma unroll
        for (int q = 0; q < CH1; q++) M = fmaxf(M, Pm[(size_t)(bh * CH1 + q) * A_ + t]);
        float L = 0.0f;
#pragma unroll
        for (int q = 0; q < CH1; q++) {
            float f = __expf(Pm[(size_t)(bh * CH1 + q) * A_ + t] - M);
            F[q][t] = f;
            L = fmaf(f, Pl[(size_t)(bh * CH1 + q) * A_ + t], L);
        }
        Linv[t] = 1.0f / L;
    }
    __syncthreads();
#pragma unroll
    for (int ii = 0; ii < 3; ii++) {
        int i = t + ii * 256;
        if (i < A_ * 16) {
            int a = i >> 4, d4 = i & 15;
            float4 s4 = make_float4(0.f, 0.f, 0.f, 0.f);
            for (int q = 0; q < CH1; q++) {
                float f = F[q][a];
                float4 p4 = *(const float4*)&Pacc[(((size_t)(bh * CH1 + q) * A_) + a) * D_ + d4 * 4];
                s4.x = fmaf(f, p4.x, s4.x);
                s4.y = fmaf(f, p4.y, s4.y);
                s4.z = fmaf(f, p4.z, s4.z);
                s4.w = fmaf(f, p4.w, s4.w);
            }
            float inv = Linv[a];
            s4.x *= inv; s4.y *= inv; s4.z *= inv; s4.w *= inv;
            *(float4*)&AgV[(size_t)bh * (A_ * D_) + a * D_ + d4 * 4] = s4;
        }
    }
}

// ------- stage 2 MFMA v4 (round-14 proven): 4 chunks/block, pipelined Q via LDS ------
__global__ __launch_bounds__(256, 2) void stage2_mfma(
    const float* __restrict__ Qg,
    const unsigned short* __restrict__ AGFh, const unsigned short* __restrict__ AGFl,
    const unsigned short* __restrict__ DFh,  const unsigned short* __restrict__ DFl,
    const unsigned short* __restrict__ AVFh, const unsigned short* __restrict__ AVFl,
    float* __restrict__ Out)
{
    const int sb8 = blockIdx.x;      // 0..7 (4 chunks of 64 s)
    const int bh  = blockIdx.y;      // 0..191
    const int b = bh / H_, h = bh % H_;

    __shared__ unsigned short Qfh[8 * 64 * 8], Qfl[8 * 64 * 8];
    __shared__ float scm[64][52];
    __shared__ float scp[64][68];
    __shared__ unsigned short PAh[64][72], PAl[64][72];

    const int t = threadIdx.x;
    const int lane = t & 63, ts = t >> 6;
    const int fr = lane & 15, kg = lane >> 4;

    // hoisted AG fragments (bh-only, loop-invariant)
    short8v agh[3][2], agl[3][2];
#pragma unroll
    for (int at = 0; at < 3; at++)
#pragma unroll
        for (int ks = 0; ks < 2; ks++) {
            size_t o = ((((size_t)bh * 3 + at) * 2 + ks) * 64 + lane) * 8;
            agh[at][ks] = *(const short8v*)&AGFh[o];
            agl[at][ks] = *(const short8v*)&AGFl[o];
        }

    // Q staging geometry (v3-proven)
    const int r = t >> 2, c0 = (t & 3) * 16;
    const int tsr = r >> 4, frr = r & 15;
    const int c8a = (t & 3) * 2, c8b = c8a + 1;
    const int oa = ((tsr * 2 + (c8a >> 2)) * 64 + (((c8a & 3) << 4) | frr)) * 8;
    const int ob = ((tsr * 2 + (c8b >> 2)) * 64 + (((c8b & 3) << 4) | frr)) * 8;
    const float* qbase = Qg + ((size_t)bh * S_ + sb8 * 256 + r) * D_ + c0;

    // prologue: stage chunk 0
    {
        float4 f0 = *(const float4*)(qbase);
        float4 f1 = *(const float4*)(qbase + 4);
        float4 f2 = *(const float4*)(qbase + 8);
        float4 f3 = *(const float4*)(qbase + 12);
        float xa[8] = {f0.x, f0.y, f0.z, f0.w, f1.x, f1.y, f1.z, f1.w};
        float xb[8] = {f2.x, f2.y, f2.z, f2.w, f3.x, f3.y, f3.z, f3.w};
        int4 h0, l0, h1, l1;
        split8c(xa, h0, l0);
        split8c(xb, h1, l1);
        *(int4*)&Qfh[oa] = h0;  *(int4*)&Qfl[oa] = l0;
        *(int4*)&Qfh[ob] = h1;  *(int4*)&Qfl[ob] = l1;
    }
    __syncthreads();

    for (int c = 0; c < 4; c++) {
        const int s0 = sb8 * 256 + c * 64;
        const int base_u = (s0 >> 4) + 125;

        // q fragments from LDS (Qf for chunk c is ready)
        short8v qh[2], ql[2];
#pragma unroll
        for (int ks = 0; ks < 2; ks++) {
            qh[ks] = *(const short8v*)&Qfh[((ts * 2 + ks) * 64 + lane) * 8];
            ql[ks] = *(const short8v*)&Qfl[((ts * 2 + ks) * 64 + lane) * 8];
        }
        // issue next chunk's Q loads early (HBM latency hides under scores)
        float4 nf0, nf1, nf2, nf3;
        if (c < 3) {
            const float* np = qbase + (size_t)(c + 1) * 64 * D_;
            nf0 = *(const float4*)(np);
            nf1 = *(const float4*)(np + 4);
            nf2 = *(const float4*)(np + 8);
            nf3 = *(const float4*)(np + 12);
        }

        // ---- scores: AG (hoisted frags) ----
#pragma unroll
        for (int at = 0; at < 3; at++) {
            f32x4 acc = (f32x4){0.f, 0.f, 0.f, 0.f};
#pragma unroll
            for (int ks = 0; ks < 2; ks++) {
                acc = __builtin_amdgcn_mfma_f32_16x16x32_bf16(agh[at][ks], qh[ks], acc, 0, 0, 0);
                acc = __builtin_amdgcn_mfma_f32_16x16x32_bf16(agl[at][ks], qh[ks], acc, 0, 0, 0);
                acc = __builtin_amdgcn_mfma_f32_16x16x32_bf16(agh[at][ks], ql[ks], acc, 0, 0, 0);
            }
            *(f32x4*)&scm[ts * 16 + fr][at * 16 + kg * 4] = acc;
        }
        // ---- scores: PE band ----
#pragma unroll
        for (int o4 = 0; o4 < 4; o4++) {
            f32x4 acc = (f32x4){0.f, 0.f, 0.f, 0.f};
            const int u = base_u + ts + o4;
#pragma unroll
            for (int ks = 0; ks < 2; ks++) {
                size_t o = (((size_t)u * 2 + ks) * 64 + lane) * 8;
                short8v chv = *(const short8v*)&DFh[o];
                short8v clv = *(const short8v*)&DFl[o];
                acc = __builtin_amdgcn_mfma_f32_16x16x32_bf16(chv, qh[ks], acc, 0, 0, 0);
                acc = __builtin_amdgcn_mfma_f32_16x16x32_bf16(clv, qh[ks], acc, 0, 0, 0);
                acc = __builtin_amdgcn_mfma_f32_16x16x32_bf16(chv, ql[ks], acc, 0, 0, 0);
            }
            *(f32x4*)&scp[ts * 16 + fr][o4 * 16 + kg * 4] = acc;
        }
        __syncthreads();   // scores ready; Qf dead

        // ---- write next Qf (overlapped with softmax phase) ----
        if (c < 3) {
            float xa[8] = {nf0.x, nf0.y, nf0.z, nf0.w, nf1.x, nf1.y, nf1.z, nf1.w};
            float xb[8] = {nf2.x, nf2.y, nf2.z, nf2.w, nf3.x, nf3.y, nf3.z, nf3.w};
            int4 h0, l0, h1, l1;
            split8c(xa, h0, l0);
            split8c(xb, h1, l1);
            *(int4*)&Qfh[oa] = h0;  *(int4*)&Qfl[oa] = l0;
            *(int4*)&Qfh[ob] = h1;  *(int4*)&Qfl[ob] = l1;
        }
        // ---- softmax over a (4 threads per s-row) ----
        {
            const int rr = t >> 2, dq = t & 3;
            const int base = (rr & 15) + 39;
            float val[10];
#pragma unroll
            for (int i = 0; i < 10; i++) {
                int a = dq * 10 + i;
                val[i] = scm[rr][a] + scp[rr][base - a];
            }
            float mx = -INFINITY;
#pragma unroll
            for (int i = 0; i < 10; i++) mx = fmaxf(mx, val[i]);
            mx = fmaxf(mx, __shfl_xor(mx, 1));
            mx = fmaxf(mx, __shfl_xor(mx, 2));
            float sum = 0.f;
#pragma unroll
            for (int i = 0; i < 10; i++) { val[i] = __expf(val[i] - mx); sum += val[i]; }
            sum += __shfl_xor(sum, 1);
            sum += __shfl_xor(sum, 2);
            float inv = 1.0f / sum;
            unsigned* ph = (unsigned*)&PAh[rr][0];
            unsigned* pl = (unsigned*)&PAl[rr][0];
#pragma unroll
            for (int i = 0; i < 5; i++) {
                unsigned short hh0, ll0, hh1, ll1;
                split1(val[2 * i] * inv, hh0, ll0);
                split1(val[2 * i + 1] * inv, hh1, ll1);
                ph[dq * 5 + i] = (unsigned)hh0 | ((unsigned)hh1 << 16);
                pl[dq * 5 + i] = (unsigned)ll0 | ((unsigned)ll1 << 16);
            }
#pragma unroll
            for (int i = 0; i < 3; i++) { ph[20 + dq * 3 + i] = 0u; pl[20 + dq * 3 + i] = 0u; }
        }
        __syncthreads();   // PA ready; Qf[c+1] ready

        // ---- PV + store ----
        short8v ph8[2], pl8[2];
#pragma unroll
        for (int ks = 0; ks < 2; ks++) {
            ph8[ks] = *(const short8v*)&PAh[ts * 16 + fr][ks * 32 + kg * 8];
            pl8[ks] = *(const short8v*)&PAl[ts * 16 + fr][ks * 32 + kg * 8];
        }
#pragma unroll
        for (int nt = 0; nt < 4; nt++) {
            f32x4 acc = (f32x4){0.f, 0.f, 0.f, 0.f};
#pragma unroll
            for (int ks = 0; ks < 2; ks++) {
                size_t o = ((((size_t)bh * 4 + nt) * 2 + ks) * 64 + lane) * 8;
                short8v vh = *(const short8v*)&AVFh[o];
                short8v vl = *(const short8v*)&AVFl[o];
                acc = __builtin_amdgcn_mfma_f32_16x16x32_bf16(ph8[ks], vh, acc, 0, 0, 0);
                acc = __builtin_amdgcn_mfma_f32_16x16x32_bf16(pl8[ks], vh, acc, 0, 0, 0);
                acc = __builtin_amdgcn_mfma_f32_16x16x32_bf16(ph8[ks], vl, acc, 0, 0, 0);
            }
            const int d = nt * 16 + fr;
            float* op = Out + ((size_t)b * S_ + s0 + ts * 16 + kg * 4) * HID + h * D_ + d;
#pragma unroll
            for (int rr = 0; rr < 4; rr++)
                op[(size_t)rr * HID] = acc[rr];
        }
        __syncthreads();   // PA/scm/scp dead before next chunk's scores
    }
}

extern "C" void kernel_launch(void* const* d_in, const int* in_sizes, int n_in,
                              void* d_out, int out_size, void* d_ws, size_t ws_size,
                              hipStream_t stream) {
    const float* hs   = (const float*)d_in[0];
    const float* mask = (const float*)d_in[1];
    const float* Wq   = (const float*)d_in[2];
    const float* bq   = (const float*)d_in[3];
    const float* Wk   = (const float*)d_in[4];
    const float* bk   = (const float*)d_in[5];
    const float* Wv   = (const float*)d_in[6];
    const float* bv   = (const float*)d_in[7];
    const float* dist = (const float*)d_in[8];
    float* out = (float*)d_out;

    float* ws = (float*)d_ws;
    const size_t QKV = (size_t)B_ * H_ * S_ * D_;
    const size_t AG  = (size_t)B_ * H_ * A_ * D_;
    float* Q     = ws;
    float* K     = ws + QKV;
    float* V     = ws + 2 * QKV;
    float* Agent = ws + 3 * QKV;     // unused (layout stability)
    float* AgV   = Agent + AG;
    float* Pacc  = AgV + AG;
    float* Pm    = Pacc + (size_t)B_ * H_ * CH1 * A_ * D_;
    float* Pl    = Pm + (size_t)B_ * H_ * CH1 * A_;
    unsigned short* Wth = (unsigned short*)(Pl + (size_t)B_ * H_ * CH1 * A_);
    unsigned short* Wtl = Wth + (size_t)3 * HID * HID;
    unsigned short* DFh = Wtl + (size_t)3 * HID * HID;
    unsigned short* DFl = DFh + (size_t)262144;
    unsigned short* AGFh = DFl + (size_t)262144;
    unsigned short* AGFl = AGFh + (size_t)589824;
    unsigned short* AVFh = AGFl + (size_t)589824;
    unsigned short* AVFl = AVFh + (size_t)786432;
    unsigned short* AG1h = AVFl + (size_t)786432;
    unsigned short* AG1l = AG1h + (size_t)589824;
    unsigned short* D0h  = AG1l + (size_t)589824;
    unsigned short* D0l  = D0h + (size_t)134144;
    // total ws ~340 MB (within known-good <=393 MB budget)

    preconvert<<<WT_BLKS + DF_BLKS + D0_BLKS, 256, 0, stream>>>(
        Wq, Wk, Wv, dist, Wth, Wtl, DFh, DFl, D0h, D0l);
    qkv_z<<<2304, 512, 0, stream>>>(hs, Wth, Wtl, bq, bk, bv, Q, K, V);
    agpool_frag<<<B_ * H_, 256, 0, stream>>>(Q, AGFh, AGFl, AG1h, AG1l);
    dim3 g1(CH1, B_ * H_);
    stage1_mfma<<<g1, 256, 0, stream>>>(K, V, AG1h, AG1l, D0h, D0l, mask, Pacc, Pm, Pl);
    stage1_reduce<<<B_ * H_, 256, 0, stream>>>(Pacc, Pm, Pl, AgV);
    avt_frag<<<(192 * 4 * 2 * 64 + 255) / 256, 256, 0, stream>>>(AgV, AVFh, AVFl);
    dim3 g2(8, B_ * H_);
    stage2_mfma<<<g2, 256, 0, stream>>>(Q, AGFh, AGFl, DFh, DFl, AVFh, AVFl, out);
}

// Round 18
// 546.508 us; speedup vs baseline: 1.0663x; 1.0212x over previous
//
#include <hip/hip_runtime.h>
#include <math.h>

#define B_ 16
#define S_ 2048
#define H_ 12
#define D_ 64
#define HID 768
#define A_ 40
#define SCALE_ 0.125f
#define CH1 8          // stage1 s-chunks per (b,h)
#define SUBT 64        // s per subtile
#define NSUB 4         // subtiles per block (256 s per block)

typedef __attribute__((ext_vector_type(8))) short short8v;    // 8 bf16 (4 VGPR)
typedef __attribute__((ext_vector_type(4))) float f32x4;
typedef __attribute__((ext_vector_type(16))) float f32x16;    // 32x32 MFMA C/D

__device__ __forceinline__ unsigned f2bf_bits(float x) {
    unsigned u = __float_as_uint(x);
    return (u + 0x7FFFu + ((u >> 16) & 1u)) >> 16;   // RTNE
}

__device__ __forceinline__ void split1(float v, unsigned short& h, unsigned short& l) {
    __bf16 bh = (__bf16)v;
    float hf = (float)bh;
    __bf16 bl = (__bf16)(v - hf);
    h = __builtin_bit_cast(unsigned short, bh);
    l = __builtin_bit_cast(unsigned short, bl);
}

// split 8 fp32 -> hi/lo bf16 via native __bf16 casts (RTNE)
__device__ __forceinline__ void split8c(const float* x, int4& hi, int4& lo) {
    unsigned h[8], l[8];
#pragma unroll
    for (int i = 0; i < 8; i++) {
        __bf16 bh = (__bf16)x[i];
        float hf = (float)bh;
        __bf16 bl = (__bf16)(x[i] - hf);
        h[i] = (unsigned)__builtin_bit_cast(unsigned short, bh);
        l[i] = (unsigned)__builtin_bit_cast(unsigned short, bl);
    }
    hi = make_int4((int)(h[0] | (h[1] << 16)), (int)(h[2] | (h[3] << 16)),
                   (int)(h[4] | (h[5] << 16)), (int)(h[6] | (h[7] << 16)));
    lo = make_int4((int)(l[0] | (l[1] << 16)), (int)(l[2] | (l[3] << 16)),
                   (int)(l[4] | (l[5] << 16)), (int)(l[6] | (l[7] << 16)));
}

// ------- merged input preconvert: W transpose/split + dist frag tables ----------
#define WT_BLKS 1728   // 3*192*768 / 256
#define DF_BLKS 128    // 256*2*64 / 256
#define D0_BLKS 66     // ceil(131*2*64 / 256)
__global__ __launch_bounds__(256) void preconvert(
    const float* __restrict__ Wq, const float* __restrict__ Wk, const float* __restrict__ Wv,
    const float* __restrict__ dist,
    unsigned short* __restrict__ Wth, unsigned short* __restrict__ Wtl,
    unsigned short* __restrict__ DFh, unsigned short* __restrict__ DFl,
    unsigned short* __restrict__ D0h, unsigned short* __restrict__ D0l)
{
    const int bx = blockIdx.x;
    const int t = threadIdx.x;
    if (bx < WT_BLKS) {
        int idx = bx * 256 + t;
        if (idx >= 3 * 192 * 768) return;
        int n  = idx % 768;
        int kc = (idx / 768) % 192;
        int z  = idx / (768 * 192);
        const float* W = (z == 0) ? Wq : (z == 1) ? Wk : Wv;
        unsigned short h4[4], l4[4];
#pragma unroll
        for (int i = 0; i < 4; i++) {
            float x = W[(size_t)(4 * kc + i) * HID + n];
            unsigned hb = f2bf_bits(x);
            float hf = __uint_as_float(hb << 16);
            h4[i] = (unsigned short)hb;
            l4[i] = (unsigned short)f2bf_bits(x - hf);
        }
        size_t o = ((size_t)z * HID + n) * HID + 4 * kc;
        *(ushort4*)&Wth[o] = make_ushort4(h4[0], h4[1], h4[2], h4[3]);
        *(ushort4*)&Wtl[o] = make_ushort4(l4[0], l4[1], l4[2], l4[3]);
    } else if (bx < WT_BLKS + DF_BLKS) {
        int g = (bx - WT_BLKS) * 256 + t;
        int lane = g & 63;
        int ks = (g >> 6) & 1;
        int u  = g >> 7;
        int row = 8 + u * 16 + (lane & 15);
        int col = ks * 32 + ((lane >> 4) << 3);
        float xv[8];
#pragma unroll
        for (int j = 0; j < 8; j++)
            xv[j] = (row < 4095) ? dist[(size_t)row * D_ + col + j] : 0.f;
        int4 hi, lo;
        split8c(xv, hi, lo);
        *(int4*)&DFh[(size_t)g * 8] = hi;
        *(int4*)&DFl[(size_t)g * 8] = lo;
    } else {
        int g = (bx - WT_BLKS - DF_BLKS) * 256 + t;
        if (g >= 131 * 2 * 64) return;
        int lane = g & 63;
        int ks = (g >> 6) & 1;
        int u  = g >> 7;
        int row = u * 16 + (lane & 15);
        int col = ks * 32 + ((lane >> 4) << 3);
        float xv[8];
#pragma unroll
        for (int j = 0; j < 8; j++) xv[j] = dist[(size_t)row * D_ + col + j];
        int4 hi, lo;
        split8c(xv, hi, lo);
        *(int4*)&D0h[(size_t)g * 8] = hi;
        *(int4*)&D0l[(size_t)g * 8] = lo;
    }
}

// ------- AgV^T -> fragment-major: [bh][nt<4][ks][lane][8] rows=d, cols=a ----------
__global__ void avt_frag(const float* __restrict__ AgV,
                         unsigned short* __restrict__ Vh, unsigned short* __restrict__ Vl)
{
    int g = blockIdx.x * 256 + threadIdx.x;   // 192*4*2*64
    if (g >= 192 * 4 * 2 * 64) return;
    int lane = g & 63;
    int r = g >> 6;
    int ks = r & 1; r >>= 1;
    int nt = r & 3;
    int bh = r >> 2;
    int d = nt * 16 + (lane & 15);
    int a0 = ks * 32 + ((lane >> 4) << 3);
    float xv[8];
#pragma unroll
    for (int j = 0; j < 8; j++) {
        int a = a0 + j;
        xv[j] = (a < A_) ? AgV[((size_t)bh * A_ + a) * D_ + d] : 0.f;
    }
    int4 hi, lo;
    split8c(xv, hi, lo);
    *(int4*)&Vh[(size_t)g * 8] = hi;
    *(int4*)&Vl[(size_t)g * 8] = lo;
}

// ---------------- QKV: bf16x3 MFMA GEMM (32x32x16), 128x256 tile, XCD-swizzled ----------
__global__ __launch_bounds__(512, 2) void qkv_z(
    const float* __restrict__ X,
    const unsigned short* __restrict__ Wth, const unsigned short* __restrict__ Wtl,
    const float* __restrict__ bq, const float* __restrict__ bk, const float* __restrict__ bv,
    float* __restrict__ Q, float* __restrict__ K, float* __restrict__ V)
{
    const int L   = blockIdx.x;
    const int k8  = L & 7, sl_ = L >> 3;
    const int mt  = k8 * 32 + sl_ / 9;
    const int sub = sl_ % 9;
    const int nt  = sub % 3, zz = sub / 3;
    const int m0 = mt * 128, n0 = nt * 256;

    const float* __restrict__ bias = (zz == 0) ? bq : (zz == 1) ? bk : bv;
    float* __restrict__ Out        = (zz == 0) ? Q  : (zz == 1) ? K  : V;
    const unsigned short* __restrict__ Bhg = Wth + (size_t)zz * HID * HID;
    const unsigned short* __restrict__ Blg = Wtl + (size_t)zz * HID * HID;

    __shared__ unsigned short Ah[128][40];
    __shared__ unsigned short Al[128][40];
    __shared__ unsigned short Bh[256][40];
    __shared__ unsigned short Bl[256][40];

    const int t = threadIdx.x;
    const int lane = t & 63, w = t >> 6;
    const int wm = (w & 1) * 64, wn = (w >> 1) * 64;
    const int r32 = lane & 31, kh = lane >> 5;

    const int sr = t >> 2, sca = (t & 3) * 8;
    const int sb = t >> 1, scb = (t & 1) * 16;

    f32x16 acc[2][2];
#pragma unroll
    for (int i = 0; i < 2; i++)
#pragma unroll
        for (int j = 0; j < 2; j++)
#pragma unroll
            for (int p = 0; p < 16; p++) acc[i][j][p] = 0.f;

    for (int k0 = 0; k0 < HID; k0 += 32) {
        float xv[8];
        const float* xp = X + (size_t)(m0 + sr) * HID + k0 + sca;
        float4 f0 = *(const float4*)xp;
        float4 f1 = *(const float4*)(xp + 4);
        xv[0] = f0.x; xv[1] = f0.y; xv[2] = f0.z; xv[3] = f0.w;
        xv[4] = f1.x; xv[5] = f1.y; xv[6] = f1.z; xv[7] = f1.w;
        int4 ah, al;
        split8c(xv, ah, al);
        size_t bo = (size_t)(n0 + sb) * HID + k0 + scb;
        int4 bh0 = *(const int4*)&Bhg[bo];
        int4 bh1 = *(const int4*)&Bhg[bo + 8];
        int4 bl0 = *(const int4*)&Blg[bo];
        int4 bl1 = *(const int4*)&Blg[bo + 8];

        __syncthreads();
        *(int4*)&Ah[sr][sca] = ah;
        *(int4*)&Al[sr][sca] = al;
        *(int4*)&Bh[sb][scb]     = bh0;  *(int4*)&Bh[sb][scb + 8] = bh1;
        *(int4*)&Bl[sb][scb]     = bl0;  *(int4*)&Bl[sb][scb + 8] = bl1;
        __syncthreads();

#pragma unroll
        for (int ks = 0; ks < 2; ks++) {
            const int ko = ks * 16 + kh * 8;
            short8v a_h[2], a_l[2], b_h[2], b_l[2];
#pragma unroll
            for (int i = 0; i < 2; i++) {
                a_h[i] = *(const short8v*)&Ah[wm + i * 32 + r32][ko];
                a_l[i] = *(const short8v*)&Al[wm + i * 32 + r32][ko];
                b_h[i] = *(const short8v*)&Bh[wn + i * 32 + r32][ko];
                b_l[i] = *(const short8v*)&Bl[wn + i * 32 + r32][ko];
            }
#pragma unroll
            for (int i = 0; i < 2; i++)
#pragma unroll
                for (int j = 0; j < 2; j++) {
                    acc[i][j] = __builtin_amdgcn_mfma_f32_32x32x16_bf16(a_h[i], b_h[j], acc[i][j], 0, 0, 0);
                    acc[i][j] = __builtin_amdgcn_mfma_f32_32x32x16_bf16(a_l[i], b_h[j], acc[i][j], 0, 0, 0);
                    acc[i][j] = __builtin_amdgcn_mfma_f32_32x32x16_bf16(a_h[i], b_l[j], acc[i][j], 0, 0, 0);
                }
        }
    }

    const float scl = (zz == 1) ? SCALE_ : 1.0f;
#pragma unroll
    for (int j = 0; j < 2; j++) {
        int n = n0 + wn + j * 32 + r32;
        float bj = bias[n];
        int h = n >> 6, d = n & 63;
#pragma unroll
        for (int i = 0; i < 2; i++) {
#pragma unroll
            for (int p = 0; p < 16; p++) {
                int m = m0 + wm + i * 32 + (p & 3) + 8 * (p >> 2) + 4 * kh;
                int b = m >> 11, s = m & 2047;
                Out[(((size_t)b * H_ + h) * S_ + s) * D_ + d] = (acc[i][j][p] + bj) * scl;
            }
        }
    }
}

// ------- agent pooling + AG fragment tables ----------
__global__ __launch_bounds__(256) void agpool_frag(
    const float* __restrict__ Q,
    unsigned short* __restrict__ AGFh, unsigned short* __restrict__ AGFl,
    unsigned short* __restrict__ AG1h, unsigned short* __restrict__ AG1l)
{
    const int bh = blockIdx.x;
    const int t = threadIdx.x;
    __shared__ float ag[A_][D_];
    const float* base = Q + (size_t)bh * (S_ * D_);
    for (int i = t; i < A_ * D_; i += 256) {
        int d = i & 63, a = i >> 6;
        float src = ((float)a + 0.5f) * (2048.0f / 40.0f) - 0.5f;
        src = fminf(fmaxf(src, 0.0f), 2047.0f);
        int lo = (int)floorf(src);
        int hi = min(lo + 1, S_ - 1);
        float w = src - (float)lo;
        ag[a][d] = base[lo * D_ + d] * (1.0f - w) + base[hi * D_ + d] * w;
    }
    __syncthreads();
    for (int g = t; g < 384; g += 256) {
        int lane = g & 63;
        int ks = (g >> 6) & 1;
        int at = g >> 7;
        int a = at * 16 + (lane & 15);
        int col = ks * 32 + ((lane >> 4) << 3);
        float xs[8], x1[8];
#pragma unroll
        for (int j = 0; j < 8; j++) {
            float v = (a < A_) ? ag[a][col + j] : 0.f;
            x1[j] = v; xs[j] = v * SCALE_;
        }
        int4 h1, l1, h2, l2;
        split8c(xs, h1, l1);
        split8c(x1, h2, l2);
        size_t o = ((((size_t)bh * 3 + at) * 2 + ks) * 64 + lane) * 8;
        *(int4*)&AGFh[o] = h1;  *(int4*)&AGFl[o] = l1;
        *(int4*)&AG1h[o] = h2;  *(int4*)&AG1l[o] = l2;
    }
}

// ---------------- stage 1 MFMA (round-13 proven) ----------------
__global__ __launch_bounds__(256, 2) void stage1_mfma(
    const float* __restrict__ Kl, const float* __restrict__ Vl,
    const unsigned short* __restrict__ AG1h, const unsigned short* __restrict__ AG1l,
    const unsigned short* __restrict__ D0h,  const unsigned short* __restrict__ D0l,
    const float* __restrict__ mask,
    float* __restrict__ Pacc, float* __restrict__ Pm, float* __restrict__ Pl)
{
    const int q  = blockIdx.x;
    const int bh = blockIdx.y;
    const int b  = bh / H_;
    const int s0 = q * (NSUB * SUBT);
    const float* __restrict__ kb = Kl + (size_t)bh * (S_ * D_);
    const float* __restrict__ vb = Vl + (size_t)bh * (S_ * D_);

    __shared__ unsigned short KFh[4096], KFl[4096];
    __shared__ unsigned short VTh[4096], VTl[4096];
    __shared__ float sc[SUBT][52];
    __shared__ float scp[112][52];
    __shared__ float pm6[6][A_];
    __shared__ float mrow[A_], lrow[A_], resc[A_], mrw[SUBT];

    const int t = threadIdx.x;
    const int lane = t & 63, w = t >> 6;
    const int fr = lane & 15, kg = lane >> 4;

    if (t < A_) { mrow[t] = -INFINITY; lrow[t] = 0.0f; }

    f32x4 acc3[3];
#pragma unroll
    for (int at = 0; at < 3; at++) acc3[at] = (f32x4){0.f, 0.f, 0.f, 0.f};

    for (int st = 0; st < NSUB; st++) {
        const int sb = s0 + st * SUBT;
        const int u0 = (1984 - sb) >> 4;

        __syncthreads();

        {
            const int r = t >> 2, c0 = (t & 3) * 16;
            const float* kp = kb + (size_t)(sb + r) * D_ + c0;
            float xa[8], xb[8];
            float4 f0 = *(const float4*)(kp);
            float4 f1 = *(const float4*)(kp + 4);
            float4 f2 = *(const float4*)(kp + 8);
            float4 f3 = *(const float4*)(kp + 12);
            xa[0]=f0.x; xa[1]=f0.y; xa[2]=f0.z; xa[3]=f0.w;
            xa[4]=f1.x; xa[5]=f1.y; xa[6]=f1.z; xa[7]=f1.w;
            xb[0]=f2.x; xb[1]=f2.y; xb[2]=f2.z; xb[3]=f2.w;
            xb[4]=f3.x; xb[5]=f3.y; xb[6]=f3.z; xb[7]=f3.w;
            int4 h0, l0, h1, l1;
            split8c(xa, h0, l0);
            split8c(xb, h1, l1);
            const int tsr = r >> 4, frr = r & 15;
            const int c8a = (t & 3) * 2, c8b = c8a + 1;
            const int oa = ((tsr * 2 + (c8a >> 2)) * 64 + (((c8a & 3) << 4) | frr)) * 8;
            const int ob = ((tsr * 2 + (c8b >> 2)) * 64 + (((c8b & 3) << 4) | frr)) * 8;
            *(int4*)&KFh[oa] = h0;  *(int4*)&KFl[oa] = l0;
            *(int4*)&KFh[ob] = h1;  *(int4*)&KFl[ob] = l1;
        }
        {
            const int r = t >> 2, c0 = (t & 3) * 16;
            const float* vp = vb + (size_t)(sb + r) * D_ + c0;
            float vv[16];
            float4 g0 = *(const float4*)(vp);
            float4 g1 = *(const float4*)(vp + 4);
            float4 g2 = *(const float4*)(vp + 8);
            float4 g3 = *(const float4*)(vp + 12);
            vv[0]=g0.x; vv[1]=g0.y; vv[2]=g0.z; vv[3]=g0.w;
            vv[4]=g1.x; vv[5]=g1.y; vv[6]=g1.z; vv[7]=g1.w;
            vv[8]=g2.x; vv[9]=g2.y; vv[10]=g2.z; vv[11]=g2.w;
            vv[12]=g3.x; vv[13]=g3.y; vv[14]=g3.z; vv[15]=g3.w;
            const int ks2 = r >> 5, kgp = (r & 31) >> 3, e = r & 7;
#pragma unroll
            for (int jj = 0; jj < 16; jj++) {
                int d = c0 + jj;
                int off = (((d >> 4) * 2 + ks2) * 64 + kgp * 16 + (d & 15)) * 8 + e;
                unsigned short h, l;
                split1(vv[jj], h, l);
                VTh[off] = h; VTl[off] = l;
            }
        }
        if (t < SUBT) mrw[t] = mask[(size_t)b * S_ + sb + t];
        __syncthreads();

        {
            const int ts = w;
#pragma unroll
            for (int at = 0; at < 3; at++) {
                f32x4 a4 = (f32x4){0.f, 0.f, 0.f, 0.f};
#pragma unroll
                for (int ks = 0; ks < 2; ks++) {
                    size_t oA = ((((size_t)bh * 3 + at) * 2 + ks) * 64 + lane) * 8;
                    short8v gh = *(const short8v*)&AG1h[oA];
                    short8v gl = *(const short8v*)&AG1l[oA];
                    short8v kh2 = *(const short8v*)&KFh[((ts * 2 + ks) * 64 + lane) * 8];
                    short8v kl2 = *(const short8v*)&KFl[((ts * 2 + ks) * 64 + lane) * 8];
                    a4 = __builtin_amdgcn_mfma_f32_16x16x32_bf16(gh, kh2, a4, 0, 0, 0);
                    a4 = __builtin_amdgcn_mfma_f32_16x16x32_bf16(gl, kh2, a4, 0, 0, 0);
                    a4 = __builtin_amdgcn_mfma_f32_16x16x32_bf16(gh, kl2, a4, 0, 0, 0);
                }
                *(f32x4*)&sc[ts * 16 + fr][at * 16 + kg * 4] = a4;
            }
        }
        for (int ut = w; ut < 7; ut += 4) {
            const int u = u0 + ut;
#pragma unroll
            for (int at = 0; at < 3; at++) {
                f32x4 a4 = (f32x4){0.f, 0.f, 0.f, 0.f};
#pragma unroll
                for (int ks = 0; ks < 2; ks++) {
                    size_t oA = ((((size_t)bh * 3 + at) * 2 + ks) * 64 + lane) * 8;
                    short8v gh = *(const short8v*)&AG1h[oA];
                    short8v gl = *(const short8v*)&AG1l[oA];
                    size_t oD = (((size_t)u * 2 + ks) * 64 + lane) * 8;
                    short8v dh = *(const short8v*)&D0h[oD];
                    short8v dl = *(const short8v*)&D0l[oD];
                    a4 = __builtin_amdgcn_mfma_f32_16x16x32_bf16(gh, dh, a4, 0, 0, 0);
                    a4 = __builtin_amdgcn_mfma_f32_16x16x32_bf16(gl, dh, a4, 0, 0, 0);
                    a4 = __builtin_amdgcn_mfma_f32_16x16x32_bf16(gh, dl, a4, 0, 0, 0);
                }
                *(f32x4*)&scp[ut * 16 + fr][at * 16 + kg * 4] = a4;
            }
        }
        __syncthreads();

        for (int i = t; i < SUBT * A_; i += 256) {
            int rr = i / 40, aa = i - rr * 40;
            sc[rr][aa] += scp[aa + 63 - rr][aa] + mrw[rr];
        }
        __syncthreads();
        if (t < 240) {
            int a = t % 40, r6 = t / 40;
            float mx = -INFINITY;
            for (int i = r6; i < SUBT; i += 6) mx = fmaxf(mx, sc[i][a]);
            pm6[r6][a] = mx;
        }
        __syncthreads();
        if (t < A_) {
            float lm = pm6[0][t];
#pragma unroll
            for (int r6 = 1; r6 < 6; r6++) lm = fmaxf(lm, pm6[r6][t]);
            float mnew = fmaxf(mrow[t], lm);
            resc[t] = __expf(mrow[t] - mnew);
            mrow[t] = mnew;
        }
        __syncthreads();
        for (int i = t; i < SUBT * A_; i += 256) {
            int rr = i / 40, aa = i - rr * 40;
            sc[rr][aa] = __expf(sc[rr][aa] - mrow[aa]);
        }
        __syncthreads();
        if (t < 240) {
            int a = t % 40, r6 = t / 40;
            float sm = 0.0f;
            for (int i = r6; i < SUBT; i += 6) sm += sc[i][a];
            pm6[r6][a] = sm;
        }
        __syncthreads();
        if (t < A_) {
            float ls = pm6[0][t] + pm6[1][t] + pm6[2][t] + pm6[3][t] + pm6[4][t] + pm6[5][t];
            lrow[t] = lrow[t] * resc[t] + ls;
        }
        __syncthreads();

        for (int g = t; g < 384; g += 256) {
            int pl = g & 63;
            int c = g >> 6;
            int at = c >> 1, ks2 = c & 1;
            int a = at * 16 + (pl & 15);
            int sl0 = ks2 * 32 + (pl >> 4) * 8;
            float xv[8];
#pragma unroll
            for (int e = 0; e < 8; e++)
                xv[e] = (a < A_) ? sc[sl0 + e][a] : 0.f;
            int4 hi, lo;
            split8c(xv, hi, lo);
            *(int4*)&KFh[g * 8] = hi;
            *(int4*)&KFl[g * 8] = lo;
        }
        __syncthreads();

        {
            const int dt = w;
#pragma unroll
            for (int at = 0; at < 3; at++) {
                f32x4 a4 = acc3[at];
#pragma unroll
                for (int p = 0; p < 4; p++) {
                    int a = at * 16 + kg * 4 + p;
                    float rs = (a < A_) ? resc[a] : 0.f;
                    a4[p] *= rs;
                }
#pragma unroll
                for (int ks2 = 0; ks2 < 2; ks2++) {
                    short8v ph = *(const short8v*)&KFh[((at * 2 + ks2) * 64 + lane) * 8];
                    short8v pll = *(const short8v*)&KFl[((at * 2 + ks2) * 64 + lane) * 8];
                    short8v vh = *(const short8v*)&VTh[((dt * 2 + ks2) * 64 + lane) * 8];
                    short8v vl = *(const short8v*)&VTl[((dt * 2 + ks2) * 64 + lane) * 8];
                    a4 = __builtin_amdgcn_mfma_f32_16x16x32_bf16(ph, vh, a4, 0, 0, 0);
                    a4 = __builtin_amdgcn_mfma_f32_16x16x32_bf16(pll, vh, a4, 0, 0, 0);
                    a4 = __builtin_amdgcn_mfma_f32_16x16x32_bf16(ph, vl, a4, 0, 0, 0);
                }
                acc3[at] = a4;
            }
        }
    }
    __syncthreads();

    {
        const int dt = w;
#pragma unroll
        for (int at = 0; at < 3; at++) {
#pragma unroll
            for (int p = 0; p < 4; p++) {
                int a = at * 16 + kg * 4 + p;
                if (a < A_)
                    Pacc[(((size_t)(bh * CH1 + q) * A_) + a) * D_ + dt * 16 + fr] = acc3[at][p];
            }
        }
    }
    if (t < A_) {
        Pm[(size_t)(bh * CH1 + q) * A_ + t] = mrow[t];
        Pl[(size_t)(bh * CH1 + q) * A_ + t] = lrow[t];
    }
}

// ---------------- stage 1 reduce ----------------
__global__ __launch_bounds__(256) void stage1_reduce(
    const float* __restrict__ Pacc, const float* __restrict__ Pm,
    const float* __restrict__ Pl, float* __restrict__ AgV)
{
    const int bh = blockIdx.x;
    const int t = threadIdx.x;
    __shared__ float F[CH1][A_], Linv[A_];
    if (t < A_) {
        float M = -INFINITY;
#pragma unroll
        for (int q = 0; q < CH1; q++) M = fmaxf(M, Pm[(size_t)(bh * CH1 + q) * A_ + t]);
        float L = 0.0f;
#pragma unroll
        for (int q = 0; q < CH1; q++) {
            float f = __expf(Pm[(size_t)(bh * CH1 + q) * A_ + t] - M);
            F[q][t] = f;
            L = fmaf(f, Pl[(size_t)(bh * CH1 + q) * A_ + t], L);
        }
        Linv[t] = 1.0f / L;
    }
    __syncthreads();
#pragma unroll
    for (int ii = 0; ii < 3; ii++) {
        int i = t + ii * 256;
        if (i < A_ * 16) {
            int a = i >> 4, d4 = i & 15;
            float4 s4 = make_float4(0.f, 0.f, 0.f, 0.f);
            for (int q = 0; q < CH1; q++) {
                float f = F[q][a];
                float4 p4 = *(const float4*)&Pacc[(((size_t)(bh * CH1 + q) * A_) + a) * D_ + d4 * 4];
                s4.x = fmaf(f, p4.x, s4.x);
                s4.y = fmaf(f, p4.y, s4.y);
                s4.z = fmaf(f, p4.z, s4.z);
                s4.w = fmaf(f, p4.w, s4.w);
            }
            float inv = Linv[a];
            s4.x *= inv; s4.y *= inv; s4.z *= inv; s4.w *= inv;
            *(float4*)&AgV[(size_t)bh * (A_ * D_) + a * D_ + d4 * 4] = s4;
        }
    }
}

// ------- stage 2 MFMA v6: v4 + batched table operand loads + 2 barriers/chunk ------
__global__ __launch_bounds__(256, 2) void stage2_mfma(
    const float* __restrict__ Qg,
    const unsigned short* __restrict__ AGFh, const unsigned short* __restrict__ AGFl,
    const unsigned short* __restrict__ DFh,  const unsigned short* __restrict__ DFl,
    const unsigned short* __restrict__ AVFh, const unsigned short* __restrict__ AVFl,
    float* __restrict__ Out)
{
    const int sb8 = blockIdx.x;      // 0..7 (4 chunks of 64 s)
    const int bh  = blockIdx.y;      // 0..191
    const int b = bh / H_, h = bh % H_;

    __shared__ unsigned short Qfh[8 * 64 * 8], Qfl[8 * 64 * 8];
    __shared__ float scm[64][52];
    __shared__ float scp[64][68];
    __shared__ unsigned short PAh[64][72], PAl[64][72];

    const int t = threadIdx.x;
    const int lane = t & 63, ts = t >> 6;
    const int fr = lane & 15, kg = lane >> 4;

    // hoisted AG fragments (bh-only, loop-invariant)
    short8v agh[3][2], agl[3][2];
#pragma unroll
    for (int at = 0; at < 3; at++)
#pragma unroll
        for (int ks = 0; ks < 2; ks++) {
            size_t o = ((((size_t)bh * 3 + at) * 2 + ks) * 64 + lane) * 8;
            agh[at][ks] = *(const short8v*)&AGFh[o];
            agl[at][ks] = *(const short8v*)&AGFl[o];
        }

    // Q staging geometry (v3-proven)
    const int r = t >> 2, c0 = (t & 3) * 16;
    const int tsr = r >> 4, frr = r & 15;
    const int c8a = (t & 3) * 2, c8b = c8a + 1;
    const int oa = ((tsr * 2 + (c8a >> 2)) * 64 + (((c8a & 3) << 4) | frr)) * 8;
    const int ob = ((tsr * 2 + (c8b >> 2)) * 64 + (((c8b & 3) << 4) | frr)) * 8;
    const float* qbase = Qg + ((size_t)bh * S_ + sb8 * 256 + r) * D_ + c0;

    // prologue: stage chunk 0
    {
        float4 f0 = *(const float4*)(qbase);
        float4 f1 = *(const float4*)(qbase + 4);
        float4 f2 = *(const float4*)(qbase + 8);
        float4 f3 = *(const float4*)(qbase + 12);
        float xa[8] = {f0.x, f0.y, f0.z, f0.w, f1.x, f1.y, f1.z, f1.w};
        float xb[8] = {f2.x, f2.y, f2.z, f2.w, f3.x, f3.y, f3.z, f3.w};
        int4 h0, l0, h1, l1;
        split8c(xa, h0, l0);
        split8c(xb, h1, l1);
        *(int4*)&Qfh[oa] = h0;  *(int4*)&Qfl[oa] = l0;
        *(int4*)&Qfh[ob] = h1;  *(int4*)&Qfl[ob] = l1;
    }
    __syncthreads();

    for (int c = 0; c < 4; c++) {
        const int s0 = sb8 * 256 + c * 64;
        const int base_u = (s0 >> 4) + 125;

        // q fragments from LDS (Qf for chunk c is ready)
        short8v qh[2], ql[2];
#pragma unroll
        for (int ks = 0; ks < 2; ks++) {
            qh[ks] = *(const short8v*)&Qfh[((ts * 2 + ks) * 64 + lane) * 8];
            ql[ks] = *(const short8v*)&Qfl[((ts * 2 + ks) * 64 + lane) * 8];
        }
        // issue next chunk's Q loads early (HBM latency hides under scores)
        float4 nf0, nf1, nf2, nf3;
        if (c < 3) {
            const float* np = qbase + (size_t)(c + 1) * 64 * D_;
            nf0 = *(const float4*)(np);
            nf1 = *(const float4*)(np + 4);
            nf2 = *(const float4*)(np + 8);
            nf3 = *(const float4*)(np + 12);
        }

        // ---- batch-load all PE operands (issue together; one L2 latency window) ----
        short8v dfh[4][2], dfl[4][2];
#pragma unroll
        for (int o4 = 0; o4 < 4; o4++)
#pragma unroll
            for (int ks = 0; ks < 2; ks++) {
                const int u = base_u + ts + o4;
                size_t o = (((size_t)u * 2 + ks) * 64 + lane) * 8;
                dfh[o4][ks] = *(const short8v*)&DFh[o];
                dfl[o4][ks] = *(const short8v*)&DFl[o];
            }

        // ---- scores: AG (hoisted frags) ----
#pragma unroll
        for (int at = 0; at < 3; at++) {
            f32x4 acc = (f32x4){0.f, 0.f, 0.f, 0.f};
#pragma unroll
            for (int ks = 0; ks < 2; ks++) {
                acc = __builtin_amdgcn_mfma_f32_16x16x32_bf16(agh[at][ks], qh[ks], acc, 0, 0, 0);
                acc = __builtin_amdgcn_mfma_f32_16x16x32_bf16(agl[at][ks], qh[ks], acc, 0, 0, 0);
                acc = __builtin_amdgcn_mfma_f32_16x16x32_bf16(agh[at][ks], ql[ks], acc, 0, 0, 0);
            }
            *(f32x4*)&scm[ts * 16 + fr][at * 16 + kg * 4] = acc;
        }
        // ---- scores: PE band (operands already in regs) ----
#pragma unroll
        for (int o4 = 0; o4 < 4; o4++) {
            f32x4 acc = (f32x4){0.f, 0.f, 0.f, 0.f};
#pragma unroll
            for (int ks = 0; ks < 2; ks++) {
                acc = __builtin_amdgcn_mfma_f32_16x16x32_bf16(dfh[o4][ks], qh[ks], acc, 0, 0, 0);
                acc = __builtin_amdgcn_mfma_f32_16x16x32_bf16(dfl[o4][ks], qh[ks], acc, 0, 0, 0);
                acc = __builtin_amdgcn_mfma_f32_16x16x32_bf16(dfh[o4][ks], ql[ks], acc, 0, 0, 0);
            }
            *(f32x4*)&scp[ts * 16 + fr][o4 * 16 + kg * 4] = acc;
        }
        __syncthreads();   // scores ready; Qf dead

        // ---- write next Qf (overlapped with softmax phase) ----
        if (c < 3) {
            float xa[8] = {nf0.x, nf0.y, nf0.z, nf0.w, nf1.x, nf1.y, nf1.z, nf1.w};
            float xb[8] = {nf2.x, nf2.y, nf2.z, nf2.w, nf3.x, nf3.y, nf3.z, nf3.w};
            int4 h0, l0, h1, l1;
            split8c(xa, h0, l0);
            split8c(xb, h1, l1);
            *(int4*)&Qfh[oa] = h0;  *(int4*)&Qfl[oa] = l0;
            *(int4*)&Qfh[ob] = h1;  *(int4*)&Qfl[ob] = l1;
        }
        // ---- batch-load all PV operands (overlap with softmax VALU) ----
        short8v avh[4][2], avl[4][2];
#pragma unroll
        for (int nt = 0; nt < 4; nt++)
#pragma unroll
            for (int ks = 0; ks < 2; ks++) {
                size_t o = ((((size_t)bh * 4 + nt) * 2 + ks) * 64 + lane) * 8;
                avh[nt][ks] = *(const short8v*)&AVFh[o];
                avl[nt][ks] = *(const short8v*)&AVFl[o];
            }
        // ---- softmax over a (4 threads per s-row) ----
        {
            const int rr = t >> 2, dq = t & 3;
            const int base = (rr & 15) + 39;
            float val[10];
#pragma unroll
            for (int i = 0; i < 10; i++) {
                int a = dq * 10 + i;
                val[i] = scm[rr][a] + scp[rr][base - a];
            }
            float mx = -INFINITY;
#pragma unroll
            for (int i = 0; i < 10; i++) mx = fmaxf(mx, val[i]);
            mx = fmaxf(mx, __shfl_xor(mx, 1));
            mx = fmaxf(mx, __shfl_xor(mx, 2));
            float sum = 0.f;
#pragma unroll
            for (int i = 0; i < 10; i++) { val[i] = __expf(val[i] - mx); sum += val[i]; }
            sum += __shfl_xor(sum, 1);
            sum += __shfl_xor(sum, 2);
            float inv = 1.0f / sum;
            unsigned* ph = (unsigned*)&PAh[rr][0];
            unsigned* pl = (unsigned*)&PAl[rr][0];
#pragma unroll
            for (int i = 0; i < 5; i++) {
                unsigned short hh0, ll0, hh1, ll1;
                split1(val[2 * i] * inv, hh0, ll0);
                split1(val[2 * i + 1] * inv, hh1, ll1);
                ph[dq * 5 + i] = (unsigned)hh0 | ((unsigned)hh1 << 16);
                pl[dq * 5 + i] = (unsigned)ll0 | ((unsigned)ll1 << 16);
            }
#pragma unroll
            for (int i = 0; i < 3; i++) { ph[20 + dq * 3 + i] = 0u; pl[20 + dq * 3 + i] = 0u; }
        }
        __syncthreads();   // PA ready; Qf[c+1] ready

        // ---- PV + store (operands already in regs) ----
        short8v ph8[2], pl8[2];
#pragma unroll
        for (int ks = 0; ks < 2; ks++) {
            ph8[ks] = *(const short8v*)&PAh[ts * 16 + fr][ks * 32 + kg * 8];
            pl8[ks] = *(const short8v*)&PAl[ts * 16 + fr][ks * 32 + kg * 8];
        }
#pragma unroll
        for (int nt = 0; nt < 4; nt++) {
            f32x4 acc = (f32x4){0.f, 0.f, 0.f, 0.f};
#pragma unroll
            for (int ks = 0; ks < 2; ks++) {
                acc = __builtin_amdgcn_mfma_f32_16x16x32_bf16(ph8[ks], avh[nt][ks], acc, 0, 0, 0);
                acc = __builtin_amdgcn_mfma_f32_16x16x32_bf16(pl8[ks], avh[nt][ks], acc, 0, 0, 0);
                acc = __builtin_amdgcn_mfma_f32_16x16x32_bf16(ph8[ks], avl[nt][ks], acc, 0, 0, 0);
            }
            const int d = nt * 16 + fr;
            float* op = Out + ((size_t)b * S_ + s0 + ts * 16 + kg * 4) * HID + h * D_ + d;
#pragma unroll
            for (int rr = 0; rr < 4; rr++)
                op[(size_t)rr * HID] = acc[rr];
        }
        // no trailing barrier: next chunk's scores writes (scm/scp) don't conflict with
        // this chunk's PV reads (PAh/PAl/AVF), and softmax(c+1)'s PA writes sit behind
        // the next scores barrier.
    }
}

extern "C" void kernel_launch(void* const* d_in, const int* in_sizes, int n_in,
                              void* d_out, int out_size, void* d_ws, size_t ws_size,
                              hipStream_t stream) {
    const float* hs   = (const float*)d_in[0];
    const float* mask = (const float*)d_in[1];
    const float* Wq   = (const float*)d_in[2];
    const float* bq   = (const float*)d_in[3];
    const float* Wk   = (const float*)d_in[4];
    const float* bk   = (const float*)d_in[5];
    const float* Wv   = (const float*)d_in[6];
    const float* bv   = (const float*)d_in[7];
    const float* dist = (const float*)d_in[8];
    float* out = (float*)d_out;

    float* ws = (float*)d_ws;
    const size_t QKV = (size_t)B_ * H_ * S_ * D_;
    const size_t AG  = (size_t)B_ * H_ * A_ * D_;
    float* Q     = ws;
    float* K     = ws + QKV;
    float* V     = ws + 2 * QKV;
    float* Agent = ws + 3 * QKV;     // unused (layout stability)
    float* AgV   = Agent + AG;
    float* Pacc  = AgV + AG;
    float* Pm    = Pacc + (size_t)B_ * H_ * CH1 * A_ * D_;
    float* Pl    = Pm + (size_t)B_ * H_ * CH1 * A_;
    unsigned short* Wth = (unsigned short*)(Pl + (size_t)B_ * H_ * CH1 * A_);
    unsigned short* Wtl = Wth + (size_t)3 * HID * HID;
    unsigned short* DFh = Wtl + (size_t)3 * HID * HID;
    unsigned short* DFl = DFh + (size_t)262144;
    unsigned short* AGFh = DFl + (size_t)262144;
    unsigned short* AGFl = AGFh + (size_t)589824;
    unsigned short* AVFh = AGFl + (size_t)589824;
    unsigned short* AVFl = AVFh + (size_t)786432;
    unsigned short* AG1h = AVFl + (size_t)786432;
    unsigned short* AG1l = AG1h + (size_t)589824;
    unsigned short* D0h  = AG1l + (size_t)589824;
    unsigned short* D0l  = D0h + (size_t)134144;
    // total ws ~340 MB (within known-good <=393 MB budget)

    preconvert<<<WT_BLKS + DF_BLKS + D0_BLKS, 256, 0, stream>>>(
        Wq, Wk, Wv, dist, Wth, Wtl, DFh, DFl, D0h, D0l);
    qkv_z<<<2304, 512, 0, stream>>>(hs, Wth, Wtl, bq, bk, bv, Q, K, V);
    agpool_frag<<<B_ * H_, 256, 0, stream>>>(Q, AGFh, AGFl, AG1h, AG1l);
    dim3 g1(CH1, B_ * H_);
    stage1_mfma<<<g1, 256, 0, stream>>>(K, V, AG1h, AG1l, D0h, D0l, mask, Pacc, Pm, Pl);
    stage1_reduce<<<B_ * H_, 256, 0, stream>>>(Pacc, Pm, Pl, AgV);
    avt_frag<<<(192 * 4 * 2 * 64 + 255) / 256, 256, 0, stream>>>(AgV, AVFh, AVFl);
    dim3 g2(8, B_ * H_);
    stage2_mfma<<<g2, 256, 0, stream>>>(Q, AGFh, AGFl, DFh, DFl, AVFh, AVFl, out);
}

// Round 19
// 537.715 us; speedup vs baseline: 1.0838x; 1.0164x over previous
//
#include <hip/hip_runtime.h>
#include <math.h>

#define B_ 16
#define S_ 2048
#define H_ 12
#define D_ 64
#define HID 768
#define A_ 40
#define SCALE_ 0.125f
#define CH1 8          // stage1 s-chunks per (b,h)
#define SUBT 64        // s per subtile
#define NSUB 4         // subtiles per block (256 s per block)

typedef __attribute__((ext_vector_type(8))) short short8v;    // 8 bf16 (4 VGPR)
typedef __attribute__((ext_vector_type(4))) float f32x4;
typedef __attribute__((ext_vector_type(16))) float f32x16;    // 32x32 MFMA C/D

__device__ __forceinline__ unsigned f2bf_bits(float x) {
    unsigned u = __float_as_uint(x);
    return (u + 0x7FFFu + ((u >> 16) & 1u)) >> 16;   // RTNE
}

__device__ __forceinline__ void split1(float v, unsigned short& h, unsigned short& l) {
    __bf16 bh = (__bf16)v;
    float hf = (float)bh;
    __bf16 bl = (__bf16)(v - hf);
    h = __builtin_bit_cast(unsigned short, bh);
    l = __builtin_bit_cast(unsigned short, bl);
}

// split 8 fp32 -> hi/lo bf16 via native __bf16 casts (RTNE)
__device__ __forceinline__ void split8c(const float* x, int4& hi, int4& lo) {
    unsigned h[8], l[8];
#pragma unroll
    for (int i = 0; i < 8; i++) {
        __bf16 bh = (__bf16)x[i];
        float hf = (float)bh;
        __bf16 bl = (__bf16)(x[i] - hf);
        h[i] = (unsigned)__builtin_bit_cast(unsigned short, bh);
        l[i] = (unsigned)__builtin_bit_cast(unsigned short, bl);
    }
    hi = make_int4((int)(h[0] | (h[1] << 16)), (int)(h[2] | (h[3] << 16)),
                   (int)(h[4] | (h[5] << 16)), (int)(h[6] | (h[7] << 16)));
    lo = make_int4((int)(l[0] | (l[1] << 16)), (int)(l[2] | (l[3] << 16)),
                   (int)(l[4] | (l[5] << 16)), (int)(l[6] | (l[7] << 16)));
}

// ------- merged input preconvert: W transpose/split + dist frag tables ----------
#define WT_BLKS 1728   // 3*192*768 / 256
#define DF_BLKS 128    // 256*2*64 / 256
#define D0_BLKS 66     // ceil(131*2*64 / 256)
__global__ __launch_bounds__(256) void preconvert(
    const float* __restrict__ Wq, const float* __restrict__ Wk, const float* __restrict__ Wv,
    const float* __restrict__ dist,
    unsigned short* __restrict__ Wth, unsigned short* __restrict__ Wtl,
    unsigned short* __restrict__ DFh, unsigned short* __restrict__ DFl,
    unsigned short* __restrict__ D0h, unsigned short* __restrict__ D0l)
{
    const int bx = blockIdx.x;
    const int t = threadIdx.x;
    if (bx < WT_BLKS) {
        int idx = bx * 256 + t;
        if (idx >= 3 * 192 * 768) return;
        int n  = idx % 768;
        int kc = (idx / 768) % 192;
        int z  = idx / (768 * 192);
        const float* W = (z == 0) ? Wq : (z == 1) ? Wk : Wv;
        unsigned short h4[4], l4[4];
#pragma unroll
        for (int i = 0; i < 4; i++) {
            float x = W[(size_t)(4 * kc + i) * HID + n];
            unsigned hb = f2bf_bits(x);
            float hf = __uint_as_float(hb << 16);
            h4[i] = (unsigned short)hb;
            l4[i] = (unsigned short)f2bf_bits(x - hf);
        }
        size_t o = ((size_t)z * HID + n) * HID + 4 * kc;
        *(ushort4*)&Wth[o] = make_ushort4(h4[0], h4[1], h4[2], h4[3]);
        *(ushort4*)&Wtl[o] = make_ushort4(l4[0], l4[1], l4[2], l4[3]);
    } else if (bx < WT_BLKS + DF_BLKS) {
        int g = (bx - WT_BLKS) * 256 + t;
        int lane = g & 63;
        int ks = (g >> 6) & 1;
        int u  = g >> 7;
        int row = 8 + u * 16 + (lane & 15);
        int col = ks * 32 + ((lane >> 4) << 3);
        float xv[8];
#pragma unroll
        for (int j = 0; j < 8; j++)
            xv[j] = (row < 4095) ? dist[(size_t)row * D_ + col + j] : 0.f;
        int4 hi, lo;
        split8c(xv, hi, lo);
        *(int4*)&DFh[(size_t)g * 8] = hi;
        *(int4*)&DFl[(size_t)g * 8] = lo;
    } else {
        int g = (bx - WT_BLKS - DF_BLKS) * 256 + t;
        if (g >= 131 * 2 * 64) return;
        int lane = g & 63;
        int ks = (g >> 6) & 1;
        int u  = g >> 7;
        int row = u * 16 + (lane & 15);
        int col = ks * 32 + ((lane >> 4) << 3);
        float xv[8];
#pragma unroll
        for (int j = 0; j < 8; j++) xv[j] = dist[(size_t)row * D_ + col + j];
        int4 hi, lo;
        split8c(xv, hi, lo);
        *(int4*)&D0h[(size_t)g * 8] = hi;
        *(int4*)&D0l[(size_t)g * 8] = lo;
    }
}

// ------- AgV^T -> fragment-major: [bh][nt<4][ks][lane][8] rows=d, cols=a ----------
__global__ void avt_frag(const float* __restrict__ AgV,
                         unsigned short* __restrict__ Vh, unsigned short* __restrict__ Vl)
{
    int g = blockIdx.x * 256 + threadIdx.x;   // 192*4*2*64
    if (g >= 192 * 4 * 2 * 64) return;
    int lane = g & 63;
    int r = g >> 6;
    int ks = r & 1; r >>= 1;
    int nt = r & 3;
    int bh = r >> 2;
    int d = nt * 16 + (lane & 15);
    int a0 = ks * 32 + ((lane >> 4) << 3);
    float xv[8];
#pragma unroll
    for (int j = 0; j < 8; j++) {
        int a = a0 + j;
        xv[j] = (a < A_) ? AgV[((size_t)bh * A_ + a) * D_ + d] : 0.f;
    }
    int4 hi, lo;
    split8c(xv, hi, lo);
    *(int4*)&Vh[(size_t)g * 8] = hi;
    *(int4*)&Vl[(size_t)g * 8] = lo;
}

// -------- QKV: bf16x3 MFMA (32x32x16), 128x256 tile, XCD-swizzled, reg-prefetch ------
__global__ __launch_bounds__(512, 2) void qkv_z(
    const float* __restrict__ X,
    const unsigned short* __restrict__ Wth, const unsigned short* __restrict__ Wtl,
    const float* __restrict__ bq, const float* __restrict__ bk, const float* __restrict__ bv,
    float* __restrict__ Q, float* __restrict__ K, float* __restrict__ V)
{
    const int L   = blockIdx.x;
    const int k8  = L & 7, sl_ = L >> 3;
    const int mt  = k8 * 32 + sl_ / 9;
    const int sub = sl_ % 9;
    const int nt  = sub % 3, zz = sub / 3;
    const int m0 = mt * 128, n0 = nt * 256;

    const float* __restrict__ bias = (zz == 0) ? bq : (zz == 1) ? bk : bv;
    float* __restrict__ Out        = (zz == 0) ? Q  : (zz == 1) ? K  : V;
    const unsigned short* __restrict__ Bhg = Wth + (size_t)zz * HID * HID;
    const unsigned short* __restrict__ Blg = Wtl + (size_t)zz * HID * HID;

    __shared__ unsigned short Ah[128][40];
    __shared__ unsigned short Al[128][40];
    __shared__ unsigned short Bh[256][40];
    __shared__ unsigned short Bl[256][40];

    const int t = threadIdx.x;
    const int lane = t & 63, w = t >> 6;
    const int wm = (w & 1) * 64, wn = (w >> 1) * 64;
    const int r32 = lane & 31, kh = lane >> 5;

    const int sr = t >> 2, sca = (t & 3) * 8;
    const int sb = t >> 1, scb = (t & 1) * 16;

    const float* __restrict__ xp0 = X + (size_t)(m0 + sr) * HID + sca;
    const unsigned short* __restrict__ bhp = Bhg + (size_t)(n0 + sb) * HID + scb;
    const unsigned short* __restrict__ blp = Blg + (size_t)(n0 + sb) * HID + scb;

    f32x16 acc[2][2];
#pragma unroll
    for (int i = 0; i < 2; i++)
#pragma unroll
        for (int j = 0; j < 2; j++)
#pragma unroll
            for (int p = 0; p < 16; p++) acc[i][j][p] = 0.f;

    // prologue: load tile 0 into regs
    float4 f0 = *(const float4*)(xp0);
    float4 f1 = *(const float4*)(xp0 + 4);
    int4 bh0 = *(const int4*)(bhp);
    int4 bh1 = *(const int4*)(bhp + 8);
    int4 bl0 = *(const int4*)(blp);
    int4 bl1 = *(const int4*)(blp + 8);

    for (int kt = 0; kt < 24; kt++) {
        // convert current A regs
        float xv[8] = {f0.x, f0.y, f0.z, f0.w, f1.x, f1.y, f1.z, f1.w};
        int4 ah, al;
        split8c(xv, ah, al);

        __syncthreads();   // prior tile's LDS reads complete
        *(int4*)&Ah[sr][sca] = ah;
        *(int4*)&Al[sr][sca] = al;
        *(int4*)&Bh[sb][scb]     = bh0;  *(int4*)&Bh[sb][scb + 8] = bh1;
        *(int4*)&Bl[sb][scb]     = bl0;  *(int4*)&Bl[sb][scb + 8] = bl1;
        __syncthreads();

        // issue NEXT tile's loads now -> latency hides under the MFMA phase
        if (kt < 23) {
            const int k0n = (kt + 1) * 32;
            f0  = *(const float4*)(xp0 + k0n);
            f1  = *(const float4*)(xp0 + k0n + 4);
            bh0 = *(const int4*)(bhp + k0n);
            bh1 = *(const int4*)(bhp + k0n + 8);
            bl0 = *(const int4*)(blp + k0n);
            bl1 = *(const int4*)(blp + k0n + 8);
        }

#pragma unroll
        for (int ks = 0; ks < 2; ks++) {
            const int ko = ks * 16 + kh * 8;
            short8v a_h[2], a_l[2], b_h[2], b_l[2];
#pragma unroll
            for (int i = 0; i < 2; i++) {
                a_h[i] = *(const short8v*)&Ah[wm + i * 32 + r32][ko];
                a_l[i] = *(const short8v*)&Al[wm + i * 32 + r32][ko];
                b_h[i] = *(const short8v*)&Bh[wn + i * 32 + r32][ko];
                b_l[i] = *(const short8v*)&Bl[wn + i * 32 + r32][ko];
            }
#pragma unroll
            for (int i = 0; i < 2; i++)
#pragma unroll
                for (int j = 0; j < 2; j++) {
                    acc[i][j] = __builtin_amdgcn_mfma_f32_32x32x16_bf16(a_h[i], b_h[j], acc[i][j], 0, 0, 0);
                    acc[i][j] = __builtin_amdgcn_mfma_f32_32x32x16_bf16(a_l[i], b_h[j], acc[i][j], 0, 0, 0);
                    acc[i][j] = __builtin_amdgcn_mfma_f32_32x32x16_bf16(a_h[i], b_l[j], acc[i][j], 0, 0, 0);
                }
        }
    }

    const float scl = (zz == 1) ? SCALE_ : 1.0f;
#pragma unroll
    for (int j = 0; j < 2; j++) {
        int n = n0 + wn + j * 32 + r32;
        float bj = bias[n];
        int h = n >> 6, d = n & 63;
#pragma unroll
        for (int i = 0; i < 2; i++) {
#pragma unroll
            for (int p = 0; p < 16; p++) {
                int m = m0 + wm + i * 32 + (p & 3) + 8 * (p >> 2) + 4 * kh;
                int b = m >> 11, s = m & 2047;
                Out[(((size_t)b * H_ + h) * S_ + s) * D_ + d] = (acc[i][j][p] + bj) * scl;
            }
        }
    }
}

// ------- agent pooling + AG fragment tables ----------
__global__ __launch_bounds__(256) void agpool_frag(
    const float* __restrict__ Q,
    unsigned short* __restrict__ AGFh, unsigned short* __restrict__ AGFl,
    unsigned short* __restrict__ AG1h, unsigned short* __restrict__ AG1l)
{
    const int bh = blockIdx.x;
    const int t = threadIdx.x;
    __shared__ float ag[A_][D_];
    const float* base = Q + (size_t)bh * (S_ * D_);
    for (int i = t; i < A_ * D_; i += 256) {
        int d = i & 63, a = i >> 6;
        float src = ((float)a + 0.5f) * (2048.0f / 40.0f) - 0.5f;
        src = fminf(fmaxf(src, 0.0f), 2047.0f);
        int lo = (int)floorf(src);
        int hi = min(lo + 1, S_ - 1);
        float w = src - (float)lo;
        ag[a][d] = base[lo * D_ + d] * (1.0f - w) + base[hi * D_ + d] * w;
    }
    __syncthreads();
    for (int g = t; g < 384; g += 256) {
        int lane = g & 63;
        int ks = (g >> 6) & 1;
        int at = g >> 7;
        int a = at * 16 + (lane & 15);
        int col = ks * 32 + ((lane >> 4) << 3);
        float xs[8], x1[8];
#pragma unroll
        for (int j = 0; j < 8; j++) {
            float v = (a < A_) ? ag[a][col + j] : 0.f;
            x1[j] = v; xs[j] = v * SCALE_;
        }
        int4 h1, l1, h2, l2;
        split8c(xs, h1, l1);
        split8c(x1, h2, l2);
        size_t o = ((((size_t)bh * 3 + at) * 2 + ks) * 64 + lane) * 8;
        *(int4*)&AGFh[o] = h1;  *(int4*)&AGFl[o] = l1;
        *(int4*)&AG1h[o] = h2;  *(int4*)&AG1l[o] = l2;
    }
}

// ---------------- stage 1 MFMA (round-13 proven) ----------------
__global__ __launch_bounds__(256, 2) void stage1_mfma(
    const float* __restrict__ Kl, const float* __restrict__ Vl,
    const unsigned short* __restrict__ AG1h, const unsigned short* __restrict__ AG1l,
    const unsigned short* __restrict__ D0h,  const unsigned short* __restrict__ D0l,
    const float* __restrict__ mask,
    float* __restrict__ Pacc, float* __restrict__ Pm, float* __restrict__ Pl)
{
    const int q  = blockIdx.x;
    const int bh = blockIdx.y;
    const int b  = bh / H_;
    const int s0 = q * (NSUB * SUBT);
    const float* __restrict__ kb = Kl + (size_t)bh * (S_ * D_);
    const float* __restrict__ vb = Vl + (size_t)bh * (S_ * D_);

    __shared__ unsigned short KFh[4096], KFl[4096];
    __shared__ unsigned short VTh[4096], VTl[4096];
    __shared__ float sc[SUBT][52];
    __shared__ float scp[112][52];
    __shared__ float pm6[6][A_];
    __shared__ float mrow[A_], lrow[A_], resc[A_], mrw[SUBT];

    const int t = threadIdx.x;
    const int lane = t & 63, w = t >> 6;
    const int fr = lane & 15, kg = lane >> 4;

    if (t < A_) { mrow[t] = -INFINITY; lrow[t] = 0.0f; }

    f32x4 acc3[3];
#pragma unroll
    for (int at = 0; at < 3; at++) acc3[at] = (f32x4){0.f, 0.f, 0.f, 0.f};

    for (int st = 0; st < NSUB; st++) {
        const int sb = s0 + st * SUBT;
        const int u0 = (1984 - sb) >> 4;

        __syncthreads();

        {
            const int r = t >> 2, c0 = (t & 3) * 16;
            const float* kp = kb + (size_t)(sb + r) * D_ + c0;
            float xa[8], xb[8];
            float4 f0 = *(const float4*)(kp);
            float4 f1 = *(const float4*)(kp + 4);
            float4 f2 = *(const float4*)(kp + 8);
            float4 f3 = *(const float4*)(kp + 12);
            xa[0]=f0.x; xa[1]=f0.y; xa[2]=f0.z; xa[3]=f0.w;
            xa[4]=f1.x; xa[5]=f1.y; xa[6]=f1.z; xa[7]=f1.w;
            xb[0]=f2.x; xb[1]=f2.y; xb[2]=f2.z; xb[3]=f2.w;
            xb[4]=f3.x; xb[5]=f3.y; xb[6]=f3.z; xb[7]=f3.w;
            int4 h0, l0, h1, l1;
            split8c(xa, h0, l0);
            split8c(xb, h1, l1);
            const int tsr = r >> 4, frr = r & 15;
            const int c8a = (t & 3) * 2, c8b = c8a + 1;
            const int oa = ((tsr * 2 + (c8a >> 2)) * 64 + (((c8a & 3) << 4) | frr)) * 8;
            const int ob = ((tsr * 2 + (c8b >> 2)) * 64 + (((c8b & 3) << 4) | frr)) * 8;
            *(int4*)&KFh[oa] = h0;  *(int4*)&KFl[oa] = l0;
            *(int4*)&KFh[ob] = h1;  *(int4*)&KFl[ob] = l1;
        }
        {
            const int r = t >> 2, c0 = (t & 3) * 16;
            const float* vp = vb + (size_t)(sb + r) * D_ + c0;
            float vv[16];
            float4 g0 = *(const float4*)(vp);
            float4 g1 = *(const float4*)(vp + 4);
            float4 g2 = *(const float4*)(vp + 8);
            float4 g3 = *(const float4*)(vp + 12);
            vv[0]=g0.x; vv[1]=g0.y; vv[2]=g0.z; vv[3]=g0.w;
            vv[4]=g1.x; vv[5]=g1.y; vv[6]=g1.z; vv[7]=g1.w;
            vv[8]=g2.x; vv[9]=g2.y; vv[10]=g2.z; vv[11]=g2.w;
            vv[12]=g3.x; vv[13]=g3.y; vv[14]=g3.z; vv[15]=g3.w;
            const int ks2 = r >> 5, kgp = (r & 31) >> 3, e = r & 7;
#pragma unroll
            for (int jj = 0; jj < 16; jj++) {
                int d = c0 + jj;
                int off = (((d >> 4) * 2 + ks2) * 64 + kgp * 16 + (d & 15)) * 8 + e;
                unsigned short h, l;
                split1(vv[jj], h, l);
                VTh[off] = h; VTl[off] = l;
            }
        }
        if (t < SUBT) mrw[t] = mask[(size_t)b * S_ + sb + t];
        __syncthreads();

        {
            const int ts = w;
#pragma unroll
            for (int at = 0; at < 3; at++) {
                f32x4 a4 = (f32x4){0.f, 0.f, 0.f, 0.f};
#pragma unroll
                for (int ks = 0; ks < 2; ks++) {
                    size_t oA = ((((size_t)bh * 3 + at) * 2 + ks) * 64 + lane) * 8;
                    short8v gh = *(const short8v*)&AG1h[oA];
                    short8v gl = *(const short8v*)&AG1l[oA];
                    short8v kh2 = *(const short8v*)&KFh[((ts * 2 + ks) * 64 + lane) * 8];
                    short8v kl2 = *(const short8v*)&KFl[((ts * 2 + ks) * 64 + lane) * 8];
                    a4 = __builtin_amdgcn_mfma_f32_16x16x32_bf16(gh, kh2, a4, 0, 0, 0);
                    a4 = __builtin_amdgcn_mfma_f32_16x16x32_bf16(gl, kh2, a4, 0, 0, 0);
                    a4 = __builtin_amdgcn_mfma_f32_16x16x32_bf16(gh, kl2, a4, 0, 0, 0);
                }
                *(f32x4*)&sc[ts * 16 + fr][at * 16 + kg * 4] = a4;
            }
        }
        for (int ut = w; ut < 7; ut += 4) {
            const int u = u0 + ut;
#pragma unroll
            for (int at = 0; at < 3; at++) {
                f32x4 a4 = (f32x4){0.f, 0.f, 0.f, 0.f};
#pragma unroll
                for (int ks = 0; ks < 2; ks++) {
                    size_t oA = ((((size_t)bh * 3 + at) * 2 + ks) * 64 + lane) * 8;
                    short8v gh = *(const short8v*)&AG1h[oA];
                    short8v gl = *(const short8v*)&AG1l[oA];
                    size_t oD = (((size_t)u * 2 + ks) * 64 + lane) * 8;
                    short8v dh = *(const short8v*)&D0h[oD];
                    short8v dl = *(const short8v*)&D0l[oD];
                    a4 = __builtin_amdgcn_mfma_f32_16x16x32_bf16(gh, dh, a4, 0, 0, 0);
                    a4 = __builtin_amdgcn_mfma_f32_16x16x32_bf16(gl, dh, a4, 0, 0, 0);
                    a4 = __builtin_amdgcn_mfma_f32_16x16x32_bf16(gh, dl, a4, 0, 0, 0);
                }
                *(f32x4*)&scp[ut * 16 + fr][at * 16 + kg * 4] = a4;
            }
        }
        __syncthreads();

        for (int i = t; i < SUBT * A_; i += 256) {
            int rr = i / 40, aa = i - rr * 40;
            sc[rr][aa] += scp[aa + 63 - rr][aa] + mrw[rr];
        }
        __syncthreads();
        if (t < 240) {
            int a = t % 40, r6 = t / 40;
            float mx = -INFINITY;
            for (int i = r6; i < SUBT; i += 6) mx = fmaxf(mx, sc[i][a]);
            pm6[r6][a] = mx;
        }
        __syncthreads();
        if (t < A_) {
            float lm = pm6[0][t];
#pragma unroll
            for (int r6 = 1; r6 < 6; r6++) lm = fmaxf(lm, pm6[r6][t]);
            float mnew = fmaxf(mrow[t], lm);
            resc[t] = __expf(mrow[t] - mnew);
            mrow[t] = mnew;
        }
        __syncthreads();
        for (int i = t; i < SUBT * A_; i += 256) {
            int rr = i / 40, aa = i - rr * 40;
            sc[rr][aa] = __expf(sc[rr][aa] - mrow[aa]);
        }
        __syncthreads();
        if (t < 240) {
            int a = t % 40, r6 = t / 40;
            float sm = 0.0f;
            for (int i = r6; i < SUBT; i += 6) sm += sc[i][a];
            pm6[r6][a] = sm;
        }
        __syncthreads();
        if (t < A_) {
            float ls = pm6[0][t] + pm6[1][t] + pm6[2][t] + pm6[3][t] + pm6[4][t] + pm6[5][t];
            lrow[t] = lrow[t] * resc[t] + ls;
        }
        __syncthreads();

        for (int g = t; g < 384; g += 256) {
            int pl = g & 63;
            int c = g >> 6;
            int at = c >> 1, ks2 = c & 1;
            int a = at * 16 + (pl & 15);
            int sl0 = ks2 * 32 + (pl >> 4) * 8;
            float xv[8];
#pragma unroll
            for (int e = 0; e < 8; e++)
                xv[e] = (a < A_) ? sc[sl0 + e][a] : 0.f;
            int4 hi, lo;
            split8c(xv, hi, lo);
            *(int4*)&KFh[g * 8] = hi;
            *(int4*)&KFl[g * 8] = lo;
        }
        __syncthreads();

        {
            const int dt = w;
#pragma unroll
            for (int at = 0; at < 3; at++) {
                f32x4 a4 = acc3[at];
#pragma unroll
                for (int p = 0; p < 4; p++) {
                    int a = at * 16 + kg * 4 + p;
                    float rs = (a < A_) ? resc[a] : 0.f;
                    a4[p] *= rs;
                }
#pragma unroll
                for (int ks2 = 0; ks2 < 2; ks2++) {
                    short8v ph = *(const short8v*)&KFh[((at * 2 + ks2) * 64 + lane) * 8];
                    short8v pll = *(const short8v*)&KFl[((at * 2 + ks2) * 64 + lane) * 8];
                    short8v vh = *(const short8v*)&VTh[((dt * 2 + ks2) * 64 + lane) * 8];
                    short8v vl = *(const short8v*)&VTl[((dt * 2 + ks2) * 64 + lane) * 8];
                    a4 = __builtin_amdgcn_mfma_f32_16x16x32_bf16(ph, vh, a4, 0, 0, 0);
                    a4 = __builtin_amdgcn_mfma_f32_16x16x32_bf16(pll, vh, a4, 0, 0, 0);
                    a4 = __builtin_amdgcn_mfma_f32_16x16x32_bf16(ph, vl, a4, 0, 0, 0);
                }
                acc3[at] = a4;
            }
        }
    }
    __syncthreads();

    {
        const int dt = w;
#pragma unroll
        for (int at = 0; at < 3; at++) {
#pragma unroll
            for (int p = 0; p < 4; p++) {
                int a = at * 16 + kg * 4 + p;
                if (a < A_)
                    Pacc[(((size_t)(bh * CH1 + q) * A_) + a) * D_ + dt * 16 + fr] = acc3[at][p];
            }
        }
    }
    if (t < A_) {
        Pm[(size_t)(bh * CH1 + q) * A_ + t] = mrow[t];
        Pl[(size_t)(bh * CH1 + q) * A_ + t] = lrow[t];
    }
}

// ---------------- stage 1 reduce ----------------
__global__ __launch_bounds__(256) void stage1_reduce(
    const float* __restrict__ Pacc, const float* __restrict__ Pm,
    const float* __restrict__ Pl, float* __restrict__ AgV)
{
    const int bh = blockIdx.x;
    const int t = threadIdx.x;
    __shared__ float F[CH1][A_], Linv[A_];
    if (t < A_) {
        float M = -INFINITY;
#pragma unroll
        for (int q = 0; q < CH1; q++) M = fmaxf(M, Pm[(size_t)(bh * CH1 + q) * A_ + t]);
        float L = 0.0f;
#pragma unroll
        for (int q = 0; q < CH1; q++) {
            float f = __expf(Pm[(size_t)(bh * CH1 + q) * A_ + t] - M);
            F[q][t] = f;
            L = fmaf(f, Pl[(size_t)(bh * CH1 + q) * A_ + t], L);
        }
        Linv[t] = 1.0f / L;
    }
    __syncthreads();
#pragma unroll
    for (int ii = 0; ii < 3; ii++) {
        int i = t + ii * 256;
        if (i < A_ * 16) {
            int a = i >> 4, d4 = i & 15;
            float4 s4 = make_float4(0.f, 0.f, 0.f, 0.f);
            for (int q = 0; q < CH1; q++) {
                float f = F[q][a];
                float4 p4 = *(const float4*)&Pacc[(((size_t)(bh * CH1 + q) * A_) + a) * D_ + d4 * 4];
                s4.x = fmaf(f, p4.x, s4.x);
                s4.y = fmaf(f, p4.y, s4.y);
                s4.z = fmaf(f, p4.z, s4.z);
                s4.w = fmaf(f, p4.w, s4.w);
            }
            float inv = Linv[a];
            s4.x *= inv; s4.y *= inv; s4.z *= inv; s4.w *= inv;
            *(float4*)&AgV[(size_t)bh * (A_ * D_) + a * D_ + d4 * 4] = s4;
        }
    }
}

// ------- stage 2 MFMA v6 (round-18 proven): batched operand loads, 2 barriers/chunk ------
__global__ __launch_bounds__(256, 2) void stage2_mfma(
    const float* __restrict__ Qg,
    const unsigned short* __restrict__ AGFh, const unsigned short* __restrict__ AGFl,
    const unsigned short* __restrict__ DFh,  const unsigned short* __restrict__ DFl,
    const unsigned short* __restrict__ AVFh, const unsigned short* __restrict__ AVFl,
    float* __restrict__ Out)
{
    const int sb8 = blockIdx.x;      // 0..7 (4 chunks of 64 s)
    const int bh  = blockIdx.y;      // 0..191
    const int b = bh / H_, h = bh % H_;

    __shared__ unsigned short Qfh[8 * 64 * 8], Qfl[8 * 64 * 8];
    __shared__ float scm[64][52];
    __shared__ float scp[64][68];
    __shared__ unsigned short PAh[64][72], PAl[64][72];

    const int t = threadIdx.x;
    const int lane = t & 63, ts = t >> 6;
    const int fr = lane & 15, kg = lane >> 4;

    // hoisted AG fragments (bh-only, loop-invariant)
    short8v agh[3][2], agl[3][2];
#pragma unroll
    for (int at = 0; at < 3; at++)
#pragma unroll
        for (int ks = 0; ks < 2; ks++) {
            size_t o = ((((size_t)bh * 3 + at) * 2 + ks) * 64 + lane) * 8;
            agh[at][ks] = *(const short8v*)&AGFh[o];
            agl[at][ks] = *(const short8v*)&AGFl[o];
        }

    // Q staging geometry (v3-proven)
    const int r = t >> 2, c0 = (t & 3) * 16;
    const int tsr = r >> 4, frr = r & 15;
    const int c8a = (t & 3) * 2, c8b = c8a + 1;
    const int oa = ((tsr * 2 + (c8a >> 2)) * 64 + (((c8a & 3) << 4) | frr)) * 8;
    const int ob = ((tsr * 2 + (c8b >> 2)) * 64 + (((c8b & 3) << 4) | frr)) * 8;
    const float* qbase = Qg + ((size_t)bh * S_ + sb8 * 256 + r) * D_ + c0;

    // prologue: stage chunk 0
    {
        float4 f0 = *(const float4*)(qbase);
        float4 f1 = *(const float4*)(qbase + 4);
        float4 f2 = *(const float4*)(qbase + 8);
        float4 f3 = *(const float4*)(qbase + 12);
        float xa[8] = {f0.x, f0.y, f0.z, f0.w, f1.x, f1.y, f1.z, f1.w};
        float xb[8] = {f2.x, f2.y, f2.z, f2.w, f3.x, f3.y, f3.z, f3.w};
        int4 h0, l0, h1, l1;
        split8c(xa, h0, l0);
        split8c(xb, h1, l1);
        *(int4*)&Qfh[oa] = h0;  *(int4*)&Qfl[oa] = l0;
        *(int4*)&Qfh[ob] = h1;  *(int4*)&Qfl[ob] = l1;
    }
    __syncthreads();

    for (int c = 0; c < 4; c++) {
        const int s0 = sb8 * 256 + c * 64;
        const int base_u = (s0 >> 4) + 125;

        short8v qh[2], ql[2];
#pragma unroll
        for (int ks = 0; ks < 2; ks++) {
            qh[ks] = *(const short8v*)&Qfh[((ts * 2 + ks) * 64 + lane) * 8];
            ql[ks] = *(const short8v*)&Qfl[((ts * 2 + ks) * 64 + lane) * 8];
        }
        float4 nf0, nf1, nf2, nf3;
        if (c < 3) {
            const float* np = qbase + (size_t)(c + 1) * 64 * D_;
            nf0 = *(const float4*)(np);
            nf1 = *(const float4*)(np + 4);
            nf2 = *(const float4*)(np + 8);
            nf3 = *(const float4*)(np + 12);
        }

        // ---- batch-load all PE operands ----
        short8v dfh[4][2], dfl[4][2];
#pragma unroll
        for (int o4 = 0; o4 < 4; o4++)
#pragma unroll
            for (int ks = 0; ks < 2; ks++) {
                const int u = base_u + ts + o4;
                size_t o = (((size_t)u * 2 + ks) * 64 + lane) * 8;
                dfh[o4][ks] = *(const short8v*)&DFh[o];
                dfl[o4][ks] = *(const short8v*)&DFl[o];
            }

        // ---- scores: AG ----
#pragma unroll
        for (int at = 0; at < 3; at++) {
            f32x4 acc = (f32x4){0.f, 0.f, 0.f, 0.f};
#pragma unroll
            for (int ks = 0; ks < 2; ks++) {
                acc = __builtin_amdgcn_mfma_f32_16x16x32_bf16(agh[at][ks], qh[ks], acc, 0, 0, 0);
                acc = __builtin_amdgcn_mfma_f32_16x16x32_bf16(agl[at][ks], qh[ks], acc, 0, 0, 0);
                acc = __builtin_amdgcn_mfma_f32_16x16x32_bf16(agh[at][ks], ql[ks], acc, 0, 0, 0);
            }
            *(f32x4*)&scm[ts * 16 + fr][at * 16 + kg * 4] = acc;
        }
        // ---- scores: PE band ----
#pragma unroll
        for (int o4 = 0; o4 < 4; o4++) {
            f32x4 acc = (f32x4){0.f, 0.f, 0.f, 0.f};
#pragma unroll
            for (int ks = 0; ks < 2; ks++) {
                acc = __builtin_amdgcn_mfma_f32_16x16x32_bf16(dfh[o4][ks], qh[ks], acc, 0, 0, 0);
                acc = __builtin_amdgcn_mfma_f32_16x16x32_bf16(dfl[o4][ks], qh[ks], acc, 0, 0, 0);
                acc = __builtin_amdgcn_mfma_f32_16x16x32_bf16(dfh[o4][ks], ql[ks], acc, 0, 0, 0);
            }
            *(f32x4*)&scp[ts * 16 + fr][o4 * 16 + kg * 4] = acc;
        }
        __syncthreads();   // scores ready; Qf dead

        // ---- write next Qf (overlapped with softmax phase) ----
        if (c < 3) {
            float xa[8] = {nf0.x, nf0.y, nf0.z, nf0.w, nf1.x, nf1.y, nf1.z, nf1.w};
            float xb[8] = {nf2.x, nf2.y, nf2.z, nf2.w, nf3.x, nf3.y, nf3.z, nf3.w};
            int4 h0, l0, h1, l1;
            split8c(xa, h0, l0);
            split8c(xb, h1, l1);
            *(int4*)&Qfh[oa] = h0;  *(int4*)&Qfl[oa] = l0;
            *(int4*)&Qfh[ob] = h1;  *(int4*)&Qfl[ob] = l1;
        }
        // ---- batch-load all PV operands ----
        short8v avh[4][2], avl[4][2];
#pragma unroll
        for (int nt = 0; nt < 4; nt++)
#pragma unroll
            for (int ks = 0; ks < 2; ks++) {
                size_t o = ((((size_t)bh * 4 + nt) * 2 + ks) * 64 + lane) * 8;
                avh[nt][ks] = *(const short8v*)&AVFh[o];
                avl[nt][ks] = *(const short8v*)&AVFl[o];
            }
        // ---- softmax over a (4 threads per s-row) ----
        {
            const int rr = t >> 2, dq = t & 3;
            const int base = (rr & 15) + 39;
            float val[10];
#pragma unroll
            for (int i = 0; i < 10; i++) {
                int a = dq * 10 + i;
                val[i] = scm[rr][a] + scp[rr][base - a];
            }
            float mx = -INFINITY;
#pragma unroll
            for (int i = 0; i < 10; i++) mx = fmaxf(mx, val[i]);
            mx = fmaxf(mx, __shfl_xor(mx, 1));
            mx = fmaxf(mx, __shfl_xor(mx, 2));
            float sum = 0.f;
#pragma unroll
            for (int i = 0; i < 10; i++) { val[i] = __expf(val[i] - mx); sum += val[i]; }
            sum += __shfl_xor(sum, 1);
            sum += __shfl_xor(sum, 2);
            float inv = 1.0f / sum;
            unsigned* ph = (unsigned*)&PAh[rr][0];
            unsigned* pl = (unsigned*)&PAl[rr][0];
#pragma unroll
            for (int i = 0; i < 5; i++) {
                unsigned short hh0, ll0, hh1, ll1;
                split1(val[2 * i] * inv, hh0, ll0);
                split1(val[2 * i + 1] * inv, hh1, ll1);
                ph[dq * 5 + i] = (unsigned)hh0 | ((unsigned)hh1 << 16);
                pl[dq * 5 + i] = (unsigned)ll0 | ((unsigned)ll1 << 16);
            }
#pragma unroll
            for (int i = 0; i < 3; i++) { ph[20 + dq * 3 + i] = 0u; pl[20 + dq * 3 + i] = 0u; }
        }
        __syncthreads();   // PA ready; Qf[c+1] ready

        // ---- PV + store ----
        short8v ph8[2], pl8[2];
#pragma unroll
        for (int ks = 0; ks < 2; ks++) {
            ph8[ks] = *(const short8v*)&PAh[ts * 16 + fr][ks * 32 + kg * 8];
            pl8[ks] = *(const short8v*)&PAl[ts * 16 + fr][ks * 32 + kg * 8];
        }
#pragma unroll
        for (int nt = 0; nt < 4; nt++) {
            f32x4 acc = (f32x4){0.f, 0.f, 0.f, 0.f};
#pragma unroll
            for (int ks = 0; ks < 2; ks++) {
                acc = __builtin_amdgcn_mfma_f32_16x16x32_bf16(ph8[ks], avh[nt][ks], acc, 0, 0, 0);
                acc = __builtin_amdgcn_mfma_f32_16x16x32_bf16(pl8[ks], avh[nt][ks], acc, 0, 0, 0);
                acc = __builtin_amdgcn_mfma_f32_16x16x32_bf16(ph8[ks], avl[nt][ks], acc, 0, 0, 0);
            }
            const int d = nt * 16 + fr;
            float* op = Out + ((size_t)b * S_ + s0 + ts * 16 + kg * 4) * HID + h * D_ + d;
#pragma unroll
            for (int rr = 0; rr < 4; rr++)
                op[(size_t)rr * HID] = acc[rr];
        }
        // no trailing barrier (hazards covered by next chunk's scores barrier)
    }
}

extern "C" void kernel_launch(void* const* d_in, const int* in_sizes, int n_in,
                              void* d_out, int out_size, void* d_ws, size_t ws_size,
                              hipStream_t stream) {
    const float* hs   = (const float*)d_in[0];
    const float* mask = (const float*)d_in[1];
    const float* Wq   = (const float*)d_in[2];
    const float* bq   = (const float*)d_in[3];
    const float* Wk   = (const float*)d_in[4];
    const float* bk   = (const float*)d_in[5];
    const float* Wv   = (const float*)d_in[6];
    const float* bv   = (const float*)d_in[7];
    const float* dist = (const float*)d_in[8];
    float* out = (float*)d_out;

    float* ws = (float*)d_ws;
    const size_t QKV = (size_t)B_ * H_ * S_ * D_;
    const size_t AG  = (size_t)B_ * H_ * A_ * D_;
    float* Q     = ws;
    float* K     = ws + QKV;
    float* V     = ws + 2 * QKV;
    float* Agent = ws + 3 * QKV;     // unused (layout stability)
    float* AgV   = Agent + AG;
    float* Pacc  = AgV + AG;
    float* Pm    = Pacc + (size_t)B_ * H_ * CH1 * A_ * D_;
    float* Pl    = Pm + (size_t)B_ * H_ * CH1 * A_;
    unsigned short* Wth = (unsigned short*)(Pl + (size_t)B_ * H_ * CH1 * A_);
    unsigned short* Wtl = Wth + (size_t)3 * HID * HID;
    unsigned short* DFh = Wtl + (size_t)3 * HID * HID;
    unsigned short* DFl = DFh + (size_t)262144;
    unsigned short* AGFh = DFl + (size_t)262144;
    unsigned short* AGFl = AGFh + (size_t)589824;
    unsigned short* AVFh = AGFl + (size_t)589824;
    unsigned short* AVFl = AVFh + (size_t)786432;
    unsigned short* AG1h = AVFl + (size_t)786432;
    unsigned short* AG1l = AG1h + (size_t)589824;
    unsigned short* D0h  = AG1l + (size_t)589824;
    unsigned short* D0l  = D0h + (size_t)134144;
    // total ws ~340 MB (within known-good <=393 MB budget)

    preconvert<<<WT_BLKS + DF_BLKS + D0_BLKS, 256, 0, stream>>>(
        Wq, Wk, Wv, dist, Wth, Wtl, DFh, DFl, D0h, D0l);
    qkv_z<<<2304, 512, 0, stream>>>(hs, Wth, Wtl, bq, bk, bv, Q, K, V);
    agpool_frag<<<B_ * H_, 256, 0, stream>>>(Q, AGFh, AGFl, AG1h, AG1l);
    dim3 g1(CH1, B_ * H_);
    stage1_mfma<<<g1, 256, 0, stream>>>(K, V, AG1h, AG1l, D0h, D0l, mask, Pacc, Pm, Pl);
    stage1_reduce<<<B_ * H_, 256, 0, stream>>>(Pacc, Pm, Pl, AgV);
    avt_frag<<<(192 * 4 * 2 * 64 + 255) / 256, 256, 0, stream>>>(AgV, AVFh, AVFl);
    dim3 g2(8, B_ * H_);
    stage2_mfma<<<g2, 256, 0, stream>>>(Q, AGFh, AGFl, DFh, DFl, AVFh, AVFl, out);
}

// Round 20
// 533.747 us; speedup vs baseline: 1.0918x; 1.0074x over previous
//
#include <hip/hip_runtime.h>
#include <math.h>

#define B_ 16
#define S_ 2048
#define H_ 12
#define D_ 64
#define HID 768
#define A_ 40
#define SCALE_ 0.125f
#define CH1 8          // stage1 s-chunks per (b,h)
#define SUBT 64        // s per subtile
#define NSUB 4         // subtiles per block (256 s per block)

typedef __attribute__((ext_vector_type(8))) short short8v;    // 8 bf16 (4 VGPR)
typedef __attribute__((ext_vector_type(4))) float f32x4;
typedef __attribute__((ext_vector_type(16))) float f32x16;    // 32x32 MFMA C/D

__device__ __forceinline__ unsigned f2bf_bits(float x) {
    unsigned u = __float_as_uint(x);
    return (u + 0x7FFFu + ((u >> 16) & 1u)) >> 16;   // RTNE
}

__device__ __forceinline__ void split1(float v, unsigned short& h, unsigned short& l) {
    __bf16 bh = (__bf16)v;
    float hf = (float)bh;
    __bf16 bl = (__bf16)(v - hf);
    h = __builtin_bit_cast(unsigned short, bh);
    l = __builtin_bit_cast(unsigned short, bl);
}

// split 8 fp32 -> hi/lo bf16 via native __bf16 casts (RTNE)
__device__ __forceinline__ void split8c(const float* x, int4& hi, int4& lo) {
    unsigned h[8], l[8];
#pragma unroll
    for (int i = 0; i < 8; i++) {
        __bf16 bh = (__bf16)x[i];
        float hf = (float)bh;
        __bf16 bl = (__bf16)(x[i] - hf);
        h[i] = (unsigned)__builtin_bit_cast(unsigned short, bh);
        l[i] = (unsigned)__builtin_bit_cast(unsigned short, bl);
    }
    hi = make_int4((int)(h[0] | (h[1] << 16)), (int)(h[2] | (h[3] << 16)),
                   (int)(h[4] | (h[5] << 16)), (int)(h[6] | (h[7] << 16)));
    lo = make_int4((int)(l[0] | (l[1] << 16)), (int)(l[2] | (l[3] << 16)),
                   (int)(l[4] | (l[5] << 16)), (int)(l[6] | (l[7] << 16)));
}

// ------- merged input preconvert: W transpose/split + dist frag tables ----------
#define WT_BLKS 1728   // 3*192*768 / 256
#define DF_BLKS 128    // 256*2*64 / 256
#define D0_BLKS 66     // ceil(131*2*64 / 256)
__global__ __launch_bounds__(256) void preconvert(
    const float* __restrict__ Wq, const float* __restrict__ Wk, const float* __restrict__ Wv,
    const float* __restrict__ dist,
    unsigned short* __restrict__ Wth, unsigned short* __restrict__ Wtl,
    unsigned short* __restrict__ DFh, unsigned short* __restrict__ DFl,
    unsigned short* __restrict__ D0h, unsigned short* __restrict__ D0l)
{
    const int bx = blockIdx.x;
    const int t = threadIdx.x;
    if (bx < WT_BLKS) {
        int idx = bx * 256 + t;
        if (idx >= 3 * 192 * 768) return;
        int n  = idx % 768;
        int kc = (idx / 768) % 192;
        int z  = idx / (768 * 192);
        const float* W = (z == 0) ? Wq : (z == 1) ? Wk : Wv;
        unsigned short h4[4], l4[4];
#pragma unroll
        for (int i = 0; i < 4; i++) {
            float x = W[(size_t)(4 * kc + i) * HID + n];
            unsigned hb = f2bf_bits(x);
            float hf = __uint_as_float(hb << 16);
            h4[i] = (unsigned short)hb;
            l4[i] = (unsigned short)f2bf_bits(x - hf);
        }
        size_t o = ((size_t)z * HID + n) * HID + 4 * kc;
        *(ushort4*)&Wth[o] = make_ushort4(h4[0], h4[1], h4[2], h4[3]);
        *(ushort4*)&Wtl[o] = make_ushort4(l4[0], l4[1], l4[2], l4[3]);
    } else if (bx < WT_BLKS + DF_BLKS) {
        int g = (bx - WT_BLKS) * 256 + t;
        int lane = g & 63;
        int ks = (g >> 6) & 1;
        int u  = g >> 7;
        int row = 8 + u * 16 + (lane & 15);
        int col = ks * 32 + ((lane >> 4) << 3);
        float xv[8];
#pragma unroll
        for (int j = 0; j < 8; j++)
            xv[j] = (row < 4095) ? dist[(size_t)row * D_ + col + j] : 0.f;
        int4 hi, lo;
        split8c(xv, hi, lo);
        *(int4*)&DFh[(size_t)g * 8] = hi;
        *(int4*)&DFl[(size_t)g * 8] = lo;
    } else {
        int g = (bx - WT_BLKS - DF_BLKS) * 256 + t;
        if (g >= 131 * 2 * 64) return;
        int lane = g & 63;
        int ks = (g >> 6) & 1;
        int u  = g >> 7;
        int row = u * 16 + (lane & 15);
        int col = ks * 32 + ((lane >> 4) << 3);
        float xv[8];
#pragma unroll
        for (int j = 0; j < 8; j++) xv[j] = dist[(size_t)row * D_ + col + j];
        int4 hi, lo;
        split8c(xv, hi, lo);
        *(int4*)&D0h[(size_t)g * 8] = hi;
        *(int4*)&D0l[(size_t)g * 8] = lo;
    }
}

// -------- QKV: bf16x3 MFMA (32x32x16), 128x256 tile, XCD-swizzled, reg-prefetch ------
__global__ __launch_bounds__(512, 2) void qkv_z(
    const float* __restrict__ X,
    const unsigned short* __restrict__ Wth, const unsigned short* __restrict__ Wtl,
    const float* __restrict__ bq, const float* __restrict__ bk, const float* __restrict__ bv,
    float* __restrict__ Q, float* __restrict__ K, float* __restrict__ V)
{
    const int L   = blockIdx.x;
    const int k8  = L & 7, sl_ = L >> 3;
    const int mt  = k8 * 32 + sl_ / 9;
    const int sub = sl_ % 9;
    const int nt  = sub % 3, zz = sub / 3;
    const int m0 = mt * 128, n0 = nt * 256;

    const float* __restrict__ bias = (zz == 0) ? bq : (zz == 1) ? bk : bv;
    float* __restrict__ Out        = (zz == 0) ? Q  : (zz == 1) ? K  : V;
    const unsigned short* __restrict__ Bhg = Wth + (size_t)zz * HID * HID;
    const unsigned short* __restrict__ Blg = Wtl + (size_t)zz * HID * HID;

    __shared__ unsigned short Ah[128][40];
    __shared__ unsigned short Al[128][40];
    __shared__ unsigned short Bh[256][40];
    __shared__ unsigned short Bl[256][40];

    const int t = threadIdx.x;
    const int lane = t & 63, w = t >> 6;
    const int wm = (w & 1) * 64, wn = (w >> 1) * 64;
    const int r32 = lane & 31, kh = lane >> 5;

    const int sr = t >> 2, sca = (t & 3) * 8;
    const int sb = t >> 1, scb = (t & 1) * 16;

    const float* __restrict__ xp0 = X + (size_t)(m0 + sr) * HID + sca;
    const unsigned short* __restrict__ bhp = Bhg + (size_t)(n0 + sb) * HID + scb;
    const unsigned short* __restrict__ blp = Blg + (size_t)(n0 + sb) * HID + scb;

    f32x16 acc[2][2];
#pragma unroll
    for (int i = 0; i < 2; i++)
#pragma unroll
        for (int j = 0; j < 2; j++)
#pragma unroll
            for (int p = 0; p < 16; p++) acc[i][j][p] = 0.f;

    // prologue: load tile 0 into regs
    float4 f0 = *(const float4*)(xp0);
    float4 f1 = *(const float4*)(xp0 + 4);
    int4 bh0 = *(const int4*)(bhp);
    int4 bh1 = *(const int4*)(bhp + 8);
    int4 bl0 = *(const int4*)(blp);
    int4 bl1 = *(const int4*)(blp + 8);

    for (int kt = 0; kt < 24; kt++) {
        float xv[8] = {f0.x, f0.y, f0.z, f0.w, f1.x, f1.y, f1.z, f1.w};
        int4 ah, al;
        split8c(xv, ah, al);

        __syncthreads();
        *(int4*)&Ah[sr][sca] = ah;
        *(int4*)&Al[sr][sca] = al;
        *(int4*)&Bh[sb][scb]     = bh0;  *(int4*)&Bh[sb][scb + 8] = bh1;
        *(int4*)&Bl[sb][scb]     = bl0;  *(int4*)&Bl[sb][scb + 8] = bl1;
        __syncthreads();

        if (kt < 23) {
            const int k0n = (kt + 1) * 32;
            f0  = *(const float4*)(xp0 + k0n);
            f1  = *(const float4*)(xp0 + k0n + 4);
            bh0 = *(const int4*)(bhp + k0n);
            bh1 = *(const int4*)(bhp + k0n + 8);
            bl0 = *(const int4*)(blp + k0n);
            bl1 = *(const int4*)(blp + k0n + 8);
        }

#pragma unroll
        for (int ks = 0; ks < 2; ks++) {
            const int ko = ks * 16 + kh * 8;
            short8v a_h[2], a_l[2], b_h[2], b_l[2];
#pragma unroll
            for (int i = 0; i < 2; i++) {
                a_h[i] = *(const short8v*)&Ah[wm + i * 32 + r32][ko];
                a_l[i] = *(const short8v*)&Al[wm + i * 32 + r32][ko];
                b_h[i] = *(const short8v*)&Bh[wn + i * 32 + r32][ko];
                b_l[i] = *(const short8v*)&Bl[wn + i * 32 + r32][ko];
            }
#pragma unroll
            for (int i = 0; i < 2; i++)
#pragma unroll
                for (int j = 0; j < 2; j++) {
                    acc[i][j] = __builtin_amdgcn_mfma_f32_32x32x16_bf16(a_h[i], b_h[j], acc[i][j], 0, 0, 0);
                    acc[i][j] = __builtin_amdgcn_mfma_f32_32x32x16_bf16(a_l[i], b_h[j], acc[i][j], 0, 0, 0);
                    acc[i][j] = __builtin_amdgcn_mfma_f32_32x32x16_bf16(a_h[i], b_l[j], acc[i][j], 0, 0, 0);
                }
        }
    }

    const float scl = (zz == 1) ? SCALE_ : 1.0f;
#pragma unroll
    for (int j = 0; j < 2; j++) {
        int n = n0 + wn + j * 32 + r32;
        float bj = bias[n];
        int h = n >> 6, d = n & 63;
#pragma unroll
        for (int i = 0; i < 2; i++) {
#pragma unroll
            for (int p = 0; p < 16; p++) {
                int m = m0 + wm + i * 32 + (p & 3) + 8 * (p >> 2) + 4 * kh;
                int b = m >> 11, s = m & 2047;
                Out[(((size_t)b * H_ + h) * S_ + s) * D_ + d] = (acc[i][j][p] + bj) * scl;
            }
        }
    }
}

// ------- agent pooling + AG fragment tables ----------
__global__ __launch_bounds__(256) void agpool_frag(
    const float* __restrict__ Q,
    unsigned short* __restrict__ AGFh, unsigned short* __restrict__ AGFl,
    unsigned short* __restrict__ AG1h, unsigned short* __restrict__ AG1l)
{
    const int bh = blockIdx.x;
    const int t = threadIdx.x;
    __shared__ float ag[A_][D_];
    const float* base = Q + (size_t)bh * (S_ * D_);
    for (int i = t; i < A_ * D_; i += 256) {
        int d = i & 63, a = i >> 6;
        float src = ((float)a + 0.5f) * (2048.0f / 40.0f) - 0.5f;
        src = fminf(fmaxf(src, 0.0f), 2047.0f);
        int lo = (int)floorf(src);
        int hi = min(lo + 1, S_ - 1);
        float w = src - (float)lo;
        ag[a][d] = base[lo * D_ + d] * (1.0f - w) + base[hi * D_ + d] * w;
    }
    __syncthreads();
    for (int g = t; g < 384; g += 256) {
        int lane = g & 63;
        int ks = (g >> 6) & 1;
        int at = g >> 7;
        int a = at * 16 + (lane & 15);
        int col = ks * 32 + ((lane >> 4) << 3);
        float xs[8], x1[8];
#pragma unroll
        for (int j = 0; j < 8; j++) {
            float v = (a < A_) ? ag[a][col + j] : 0.f;
            x1[j] = v; xs[j] = v * SCALE_;
        }
        int4 h1, l1, h2, l2;
        split8c(xs, h1, l1);
        split8c(x1, h2, l2);
        size_t o = ((((size_t)bh * 3 + at) * 2 + ks) * 64 + lane) * 8;
        *(int4*)&AGFh[o] = h1;  *(int4*)&AGFl[o] = l1;
        *(int4*)&AG1h[o] = h2;  *(int4*)&AG1l[o] = l2;
    }
}

// ---------------- stage 1 MFMA (round-13 proven) ----------------
__global__ __launch_bounds__(256, 2) void stage1_mfma(
    const float* __restrict__ Kl, const float* __restrict__ Vl,
    const unsigned short* __restrict__ AG1h, const unsigned short* __restrict__ AG1l,
    const unsigned short* __restrict__ D0h,  const unsigned short* __restrict__ D0l,
    const float* __restrict__ mask,
    float* __restrict__ Pacc, float* __restrict__ Pm, float* __restrict__ Pl)
{
    const int q  = blockIdx.x;
    const int bh = blockIdx.y;
    const int b  = bh / H_;
    const int s0 = q * (NSUB * SUBT);
    const float* __restrict__ kb = Kl + (size_t)bh * (S_ * D_);
    const float* __restrict__ vb = Vl + (size_t)bh * (S_ * D_);

    __shared__ unsigned short KFh[4096], KFl[4096];
    __shared__ unsigned short VTh[4096], VTl[4096];
    __shared__ float sc[SUBT][52];
    __shared__ float scp[112][52];
    __shared__ float pm6[6][A_];
    __shared__ float mrow[A_], lrow[A_], resc[A_], mrw[SUBT];

    const int t = threadIdx.x;
    const int lane = t & 63, w = t >> 6;
    const int fr = lane & 15, kg = lane >> 4;

    if (t < A_) { mrow[t] = -INFINITY; lrow[t] = 0.0f; }

    f32x4 acc3[3];
#pragma unroll
    for (int at = 0; at < 3; at++) acc3[at] = (f32x4){0.f, 0.f, 0.f, 0.f};

    for (int st = 0; st < NSUB; st++) {
        const int sb = s0 + st * SUBT;
        const int u0 = (1984 - sb) >> 4;

        __syncthreads();

        {
            const int r = t >> 2, c0 = (t & 3) * 16;
            const float* kp = kb + (size_t)(sb + r) * D_ + c0;
            float xa[8], xb[8];
            float4 f0 = *(const float4*)(kp);
            float4 f1 = *(const float4*)(kp + 4);
            float4 f2 = *(const float4*)(kp + 8);
            float4 f3 = *(const float4*)(kp + 12);
            xa[0]=f0.x; xa[1]=f0.y; xa[2]=f0.z; xa[3]=f0.w;
            xa[4]=f1.x; xa[5]=f1.y; xa[6]=f1.z; xa[7]=f1.w;
            xb[0]=f2.x; xb[1]=f2.y; xb[2]=f2.z; xb[3]=f2.w;
            xb[4]=f3.x; xb[5]=f3.y; xb[6]=f3.z; xb[7]=f3.w;
            int4 h0, l0, h1, l1;
            split8c(xa, h0, l0);
            split8c(xb, h1, l1);
            const int tsr = r >> 4, frr = r & 15;
            const int c8a = (t & 3) * 2, c8b = c8a + 1;
            const int oa = ((tsr * 2 + (c8a >> 2)) * 64 + (((c8a & 3) << 4) | frr)) * 8;
            const int ob = ((tsr * 2 + (c8b >> 2)) * 64 + (((c8b & 3) << 4) | frr)) * 8;
            *(int4*)&KFh[oa] = h0;  *(int4*)&KFl[oa] = l0;
            *(int4*)&KFh[ob] = h1;  *(int4*)&KFl[ob] = l1;
        }
        {
            const int r = t >> 2, c0 = (t & 3) * 16;
            const float* vp = vb + (size_t)(sb + r) * D_ + c0;
            float vv[16];
            float4 g0 = *(const float4*)(vp);
            float4 g1 = *(const float4*)(vp + 4);
            float4 g2 = *(const float4*)(vp + 8);
            float4 g3 = *(const float4*)(vp + 12);
            vv[0]=g0.x; vv[1]=g0.y; vv[2]=g0.z; vv[3]=g0.w;
            vv[4]=g1.x; vv[5]=g1.y; vv[6]=g1.z; vv[7]=g1.w;
            vv[8]=g2.x; vv[9]=g2.y; vv[10]=g2.z; vv[11]=g2.w;
            vv[12]=g3.x; vv[13]=g3.y; vv[14]=g3.z; vv[15]=g3.w;
            const int ks2 = r >> 5, kgp = (r & 31) >> 3, e = r & 7;
#pragma unroll
            for (int jj = 0; jj < 16; jj++) {
                int d = c0 + jj;
                int off = (((d >> 4) * 2 + ks2) * 64 + kgp * 16 + (d & 15)) * 8 + e;
                unsigned short h, l;
                split1(vv[jj], h, l);
                VTh[off] = h; VTl[off] = l;
            }
        }
        if (t < SUBT) mrw[t] = mask[(size_t)b * S_ + sb + t];
        __syncthreads();

        {
            const int ts = w;
#pragma unroll
            for (int at = 0; at < 3; at++) {
                f32x4 a4 = (f32x4){0.f, 0.f, 0.f, 0.f};
#pragma unroll
                for (int ks = 0; ks < 2; ks++) {
                    size_t oA = ((((size_t)bh * 3 + at) * 2 + ks) * 64 + lane) * 8;
                    short8v gh = *(const short8v*)&AG1h[oA];
                    short8v gl = *(const short8v*)&AG1l[oA];
                    short8v kh2 = *(const short8v*)&KFh[((ts * 2 + ks) * 64 + lane) * 8];
                    short8v kl2 = *(const short8v*)&KFl[((ts * 2 + ks) * 64 + lane) * 8];
                    a4 = __builtin_amdgcn_mfma_f32_16x16x32_bf16(gh, kh2, a4, 0, 0, 0);
                    a4 = __builtin_amdgcn_mfma_f32_16x16x32_bf16(gl, kh2, a4, 0, 0, 0);
                    a4 = __builtin_amdgcn_mfma_f32_16x16x32_bf16(gh, kl2, a4, 0, 0, 0);
                }
                *(f32x4*)&sc[ts * 16 + fr][at * 16 + kg * 4] = a4;
            }
        }
        for (int ut = w; ut < 7; ut += 4) {
            const int u = u0 + ut;
#pragma unroll
            for (int at = 0; at < 3; at++) {
                f32x4 a4 = (f32x4){0.f, 0.f, 0.f, 0.f};
#pragma unroll
                for (int ks = 0; ks < 2; ks++) {
                    size_t oA = ((((size_t)bh * 3 + at) * 2 + ks) * 64 + lane) * 8;
                    short8v gh = *(const short8v*)&AG1h[oA];
                    short8v gl = *(const short8v*)&AG1l[oA];
                    size_t oD = (((size_t)u * 2 + ks) * 64 + lane) * 8;
                    short8v dh = *(const short8v*)&D0h[oD];
                    short8v dl = *(const short8v*)&D0l[oD];
                    a4 = __builtin_amdgcn_mfma_f32_16x16x32_bf16(gh, dh, a4, 0, 0, 0);
                    a4 = __builtin_amdgcn_mfma_f32_16x16x32_bf16(gl, dh, a4, 0, 0, 0);
                    a4 = __builtin_amdgcn_mfma_f32_16x16x32_bf16(gh, dl, a4, 0, 0, 0);
                }
                *(f32x4*)&scp[ut * 16 + fr][at * 16 + kg * 4] = a4;
            }
        }
        __syncthreads();

        for (int i = t; i < SUBT * A_; i += 256) {
            int rr = i / 40, aa = i - rr * 40;
            sc[rr][aa] += scp[aa + 63 - rr][aa] + mrw[rr];
        }
        __syncthreads();
        if (t < 240) {
            int a = t % 40, r6 = t / 40;
            float mx = -INFINITY;
            for (int i = r6; i < SUBT; i += 6) mx = fmaxf(mx, sc[i][a]);
            pm6[r6][a] = mx;
        }
        __syncthreads();
        if (t < A_) {
            float lm = pm6[0][t];
#pragma unroll
            for (int r6 = 1; r6 < 6; r6++) lm = fmaxf(lm, pm6[r6][t]);
            float mnew = fmaxf(mrow[t], lm);
            resc[t] = __expf(mrow[t] - mnew);
            mrow[t] = mnew;
        }
        __syncthreads();
        for (int i = t; i < SUBT * A_; i += 256) {
            int rr = i / 40, aa = i - rr * 40;
            sc[rr][aa] = __expf(sc[rr][aa] - mrow[aa]);
        }
        __syncthreads();
        if (t < 240) {
            int a = t % 40, r6 = t / 40;
            float sm = 0.0f;
            for (int i = r6; i < SUBT; i += 6) sm += sc[i][a];
            pm6[r6][a] = sm;
        }
        __syncthreads();
        if (t < A_) {
            float ls = pm6[0][t] + pm6[1][t] + pm6[2][t] + pm6[3][t] + pm6[4][t] + pm6[5][t];
            lrow[t] = lrow[t] * resc[t] + ls;
        }
        __syncthreads();

        for (int g = t; g < 384; g += 256) {
            int pl = g & 63;
            int c = g >> 6;
            int at = c >> 1, ks2 = c & 1;
            int a = at * 16 + (pl & 15);
            int sl0 = ks2 * 32 + (pl >> 4) * 8;
            float xv[8];
#pragma unroll
            for (int e = 0; e < 8; e++)
                xv[e] = (a < A_) ? sc[sl0 + e][a] : 0.f;
            int4 hi, lo;
            split8c(xv, hi, lo);
            *(int4*)&KFh[g * 8] = hi;
            *(int4*)&KFl[g * 8] = lo;
        }
        __syncthreads();

        {
            const int dt = w;
#pragma unroll
            for (int at = 0; at < 3; at++) {
                f32x4 a4 = acc3[at];
#pragma unroll
                for (int p = 0; p < 4; p++) {
                    int a = at * 16 + kg * 4 + p;
                    float rs = (a < A_) ? resc[a] : 0.f;
                    a4[p] *= rs;
                }
#pragma unroll
                for (int ks2 = 0; ks2 < 2; ks2++) {
                    short8v ph = *(const short8v*)&KFh[((at * 2 + ks2) * 64 + lane) * 8];
                    short8v pll = *(const short8v*)&KFl[((at * 2 + ks2) * 64 + lane) * 8];
                    short8v vh = *(const short8v*)&VTh[((dt * 2 + ks2) * 64 + lane) * 8];
                    short8v vl = *(const short8v*)&VTl[((dt * 2 + ks2) * 64 + lane) * 8];
                    a4 = __builtin_amdgcn_mfma_f32_16x16x32_bf16(ph, vh, a4, 0, 0, 0);
                    a4 = __builtin_amdgcn_mfma_f32_16x16x32_bf16(pll, vh, a4, 0, 0, 0);
                    a4 = __builtin_amdgcn_mfma_f32_16x16x32_bf16(ph, vl, a4, 0, 0, 0);
                }
                acc3[at] = a4;
            }
        }
    }
    __syncthreads();

    {
        const int dt = w;
#pragma unroll
        for (int at = 0; at < 3; at++) {
#pragma unroll
            for (int p = 0; p < 4; p++) {
                int a = at * 16 + kg * 4 + p;
                if (a < A_)
                    Pacc[(((size_t)(bh * CH1 + q) * A_) + a) * D_ + dt * 16 + fr] = acc3[at][p];
            }
        }
    }
    if (t < A_) {
        Pm[(size_t)(bh * CH1 + q) * A_ + t] = mrow[t];
        Pl[(size_t)(bh * CH1 + q) * A_ + t] = lrow[t];
    }
}

// ------- stage 1 reduce (fused with avt_frag: emits AVF fragment tables directly) -------
__global__ __launch_bounds__(256) void stage1_reduce(
    const float* __restrict__ Pacc, const float* __restrict__ Pm,
    const float* __restrict__ Pl,
    unsigned short* __restrict__ AVFh, unsigned short* __restrict__ AVFl)
{
    const int bh = blockIdx.x;
    const int t = threadIdx.x;
    __shared__ float F[CH1][A_], Linv[A_];
    __shared__ float agv[A_][D_];          // 10 KB staging of AgV for the transpose
    if (t < A_) {
        float M = -INFINITY;
#pragma unroll
        for (int q = 0; q < CH1; q++) M = fmaxf(M, Pm[(size_t)(bh * CH1 + q) * A_ + t]);
        float L = 0.0f;
#pragma unroll
        for (int q = 0; q < CH1; q++) {
            float f = __expf(Pm[(size_t)(bh * CH1 + q) * A_ + t] - M);
            F[q][t] = f;
            L = fmaf(f, Pl[(size_t)(bh * CH1 + q) * A_ + t], L);
        }
        Linv[t] = 1.0f / L;
    }
    __syncthreads();
#pragma unroll
    for (int ii = 0; ii < 3; ii++) {
        int i = t + ii * 256;
        if (i < A_ * 16) {
            int a = i >> 4, d4 = i & 15;
            float4 s4 = make_float4(0.f, 0.f, 0.f, 0.f);
            for (int q = 0; q < CH1; q++) {
                float f = F[q][a];
                float4 p4 = *(const float4*)&Pacc[(((size_t)(bh * CH1 + q) * A_) + a) * D_ + d4 * 4];
                s4.x = fmaf(f, p4.x, s4.x);
                s4.y = fmaf(f, p4.y, s4.y);
                s4.z = fmaf(f, p4.z, s4.z);
                s4.w = fmaf(f, p4.w, s4.w);
            }
            float inv = Linv[a];
            s4.x *= inv; s4.y *= inv; s4.z *= inv; s4.w *= inv;
            *(float4*)&agv[a][d4 * 4] = s4;
        }
    }
    __syncthreads();
    // emit AVF fragment-major tables (layout identical to old avt_frag)
    for (int g = t; g < 4 * 2 * 64; g += 256) {
        int lane = g & 63;
        int ks = (g >> 6) & 1;
        int nt = (g >> 7) & 3;
        int d = nt * 16 + (lane & 15);
        int a0 = ks * 32 + ((lane >> 4) << 3);
        float xv[8];
#pragma unroll
        for (int j = 0; j < 8; j++) {
            int a = a0 + j;
            xv[j] = (a < A_) ? agv[a][d] : 0.f;
        }
        int4 hi, lo;
        split8c(xv, hi, lo);
        size_t o = ((((size_t)bh * 4 + nt) * 2 + ks) * 64 + lane) * 8;
        *(int4*)&AVFh[o] = hi;
        *(int4*)&AVFl[o] = lo;
    }
}

// ------- stage 2 MFMA v6 (round-18/19 proven): batched operand loads, 2 barriers/chunk ----
__global__ __launch_bounds__(256, 2) void stage2_mfma(
    const float* __restrict__ Qg,
    const unsigned short* __restrict__ AGFh, const unsigned short* __restrict__ AGFl,
    const unsigned short* __restrict__ DFh,  const unsigned short* __restrict__ DFl,
    const unsigned short* __restrict__ AVFh, const unsigned short* __restrict__ AVFl,
    float* __restrict__ Out)
{
    const int sb8 = blockIdx.x;      // 0..7 (4 chunks of 64 s)
    const int bh  = blockIdx.y;      // 0..191
    const int b = bh / H_, h = bh % H_;

    __shared__ unsigned short Qfh[8 * 64 * 8], Qfl[8 * 64 * 8];
    __shared__ float scm[64][52];
    __shared__ float scp[64][68];
    __shared__ unsigned short PAh[64][72], PAl[64][72];

    const int t = threadIdx.x;
    const int lane = t & 63, ts = t >> 6;
    const int fr = lane & 15, kg = lane >> 4;

    short8v agh[3][2], agl[3][2];
#pragma unroll
    for (int at = 0; at < 3; at++)
#pragma unroll
        for (int ks = 0; ks < 2; ks++) {
            size_t o = ((((size_t)bh * 3 + at) * 2 + ks) * 64 + lane) * 8;
            agh[at][ks] = *(const short8v*)&AGFh[o];
            agl[at][ks] = *(const short8v*)&AGFl[o];
        }

    const int r = t >> 2, c0 = (t & 3) * 16;
    const int tsr = r >> 4, frr = r & 15;
    const int c8a = (t & 3) * 2, c8b = c8a + 1;
    const int oa = ((tsr * 2 + (c8a >> 2)) * 64 + (((c8a & 3) << 4) | frr)) * 8;
    const int ob = ((tsr * 2 + (c8b >> 2)) * 64 + (((c8b & 3) << 4) | frr)) * 8;
    const float* qbase = Qg + ((size_t)bh * S_ + sb8 * 256 + r) * D_ + c0;

    {
        float4 f0 = *(const float4*)(qbase);
        float4 f1 = *(const float4*)(qbase + 4);
        float4 f2 = *(const float4*)(qbase + 8);
        float4 f3 = *(const float4*)(qbase + 12);
        float xa[8] = {f0.x, f0.y, f0.z, f0.w, f1.x, f1.y, f1.z, f1.w};
        float xb[8] = {f2.x, f2.y, f2.z, f2.w, f3.x, f3.y, f3.z, f3.w};
        int4 h0, l0, h1, l1;
        split8c(xa, h0, l0);
        split8c(xb, h1, l1);
        *(int4*)&Qfh[oa] = h0;  *(int4*)&Qfl[oa] = l0;
        *(int4*)&Qfh[ob] = h1;  *(int4*)&Qfl[ob] = l1;
    }
    __syncthreads();

    for (int c = 0; c < 4; c++) {
        const int s0 = sb8 * 256 + c * 64;
        const int base_u = (s0 >> 4) + 125;

        short8v qh[2], ql[2];
#pragma unroll
        for (int ks = 0; ks < 2; ks++) {
            qh[ks] = *(const short8v*)&Qfh[((ts * 2 + ks) * 64 + lane) * 8];
            ql[ks] = *(const short8v*)&Qfl[((ts * 2 + ks) * 64 + lane) * 8];
        }
        float4 nf0, nf1, nf2, nf3;
        if (c < 3) {
            const float* np = qbase + (size_t)(c + 1) * 64 * D_;
            nf0 = *(const float4*)(np);
            nf1 = *(const float4*)(np + 4);
            nf2 = *(const float4*)(np + 8);
            nf3 = *(const float4*)(np + 12);
        }

        short8v dfh[4][2], dfl[4][2];
#pragma unroll
        for (int o4 = 0; o4 < 4; o4++)
#pragma unroll
            for (int ks = 0; ks < 2; ks++) {
                const int u = base_u + ts + o4;
                size_t o = (((size_t)u * 2 + ks) * 64 + lane) * 8;
                dfh[o4][ks] = *(const short8v*)&DFh[o];
                dfl[o4][ks] = *(const short8v*)&DFl[o];
            }

#pragma unroll
        for (int at = 0; at < 3; at++) {
            f32x4 acc = (f32x4){0.f, 0.f, 0.f, 0.f};
#pragma unroll
            for (int ks = 0; ks < 2; ks++) {
                acc = __builtin_amdgcn_mfma_f32_16x16x32_bf16(agh[at][ks], qh[ks], acc, 0, 0, 0);
                acc = __builtin_amdgcn_mfma_f32_16x16x32_bf16(agl[at][ks], qh[ks], acc, 0, 0, 0);
                acc = __builtin_amdgcn_mfma_f32_16x16x32_bf16(agh[at][ks], ql[ks], acc, 0, 0, 0);
            }
            *(f32x4*)&scm[ts * 16 + fr][at * 16 + kg * 4] = acc;
        }
#pragma unroll
        for (int o4 = 0; o4 < 4; o4++) {
            f32x4 acc = (f32x4){0.f, 0.f, 0.f, 0.f};
#pragma unroll
            for (int ks = 0; ks < 2; ks++) {
                acc = __builtin_amdgcn_mfma_f32_16x16x32_bf16(dfh[o4][ks], qh[ks], acc, 0, 0, 0);
                acc = __builtin_amdgcn_mfma_f32_16x16x32_bf16(dfl[o4][ks], qh[ks], acc, 0, 0, 0);
                acc = __builtin_amdgcn_mfma_f32_16x16x32_bf16(dfh[o4][ks], ql[ks], acc, 0, 0, 0);
            }
            *(f32x4*)&scp[ts * 16 + fr][o4 * 16 + kg * 4] = acc;
        }
        __syncthreads();   // scores ready; Qf dead

        if (c < 3) {
            float xa[8] = {nf0.x, nf0.y, nf0.z, nf0.w, nf1.x, nf1.y, nf1.z, nf1.w};
            float xb[8] = {nf2.x, nf2.y, nf2.z, nf2.w, nf3.x, nf3.y, nf3.z, nf3.w};
            int4 h0, l0, h1, l1;
            split8c(xa, h0, l0);
            split8c(xb, h1, l1);
            *(int4*)&Qfh[oa] = h0;  *(int4*)&Qfl[oa] = l0;
            *(int4*)&Qfh[ob] = h1;  *(int4*)&Qfl[ob] = l1;
        }
        short8v avh[4][2], avl[4][2];
#pragma unroll
        for (int nt = 0; nt < 4; nt++)
#pragma unroll
            for (int ks = 0; ks < 2; ks++) {
                size_t o = ((((size_t)bh * 4 + nt) * 2 + ks) * 64 + lane) * 8;
                avh[nt][ks] = *(const short8v*)&AVFh[o];
                avl[nt][ks] = *(const short8v*)&AVFl[o];
            }
        {
            const int rr = t >> 2, dq = t & 3;
            const int base = (rr & 15) + 39;
            float val[10];
#pragma unroll
            for (int i = 0; i < 10; i++) {
                int a = dq * 10 + i;
                val[i] = scm[rr][a] + scp[rr][base - a];
            }
            float mx = -INFINITY;
#pragma unroll
            for (int i = 0; i < 10; i++) mx = fmaxf(mx, val[i]);
            mx = fmaxf(mx, __shfl_xor(mx, 1));
            mx = fmaxf(mx, __shfl_xor(mx, 2));
            float sum = 0.f;
#pragma unroll
            for (int i = 0; i < 10; i++) { val[i] = __expf(val[i] - mx); sum += val[i]; }
            sum += __shfl_xor(sum, 1);
            sum += __shfl_xor(sum, 2);
            float inv = 1.0f / sum;
            unsigned* ph = (unsigned*)&PAh[rr][0];
            unsigned* pl = (unsigned*)&PAl[rr][0];
#pragma unroll
            for (int i = 0; i < 5; i++) {
                unsigned short hh0, ll0, hh1, ll1;
                split1(val[2 * i] * inv, hh0, ll0);
                split1(val[2 * i + 1] * inv, hh1, ll1);
                ph[dq * 5 + i] = (unsigned)hh0 | ((unsigned)hh1 << 16);
                pl[dq * 5 + i] = (unsigned)ll0 | ((unsigned)ll1 << 16);
            }
#pragma unroll
            for (int i = 0; i < 3; i++) { ph[20 + dq * 3 + i] = 0u; pl[20 + dq * 3 + i] = 0u; }
        }
        __syncthreads();   // PA ready; Qf[c+1] ready

        short8v ph8[2], pl8[2];
#pragma unroll
        for (int ks = 0; ks < 2; ks++) {
            ph8[ks] = *(const short8v*)&PAh[ts * 16 + fr][ks * 32 + kg * 8];
            pl8[ks] = *(const short8v*)&PAl[ts * 16 + fr][ks * 32 + kg * 8];
        }
#pragma unroll
        for (int nt = 0; nt < 4; nt++) {
            f32x4 acc = (f32x4){0.f, 0.f, 0.f, 0.f};
#pragma unroll
            for (int ks = 0; ks < 2; ks++) {
                acc = __builtin_amdgcn_mfma_f32_16x16x32_bf16(ph8[ks], avh[nt][ks], acc, 0, 0, 0);
                acc = __builtin_amdgcn_mfma_f32_16x16x32_bf16(pl8[ks], avh[nt][ks], acc, 0, 0, 0);
                acc = __builtin_amdgcn_mfma_f32_16x16x32_bf16(ph8[ks], avl[nt][ks], acc, 0, 0, 0);
            }
            const int d = nt * 16 + fr;
            float* op = Out + ((size_t)b * S_ + s0 + ts * 16 + kg * 4) * HID + h * D_ + d;
#pragma unroll
            for (int rr = 0; rr < 4; rr++)
                op[(size_t)rr * HID] = acc[rr];
        }
        // no trailing barrier (hazards covered by next chunk's scores barrier)
    }
}

extern "C" void kernel_launch(void* const* d_in, const int* in_sizes, int n_in,
                              void* d_out, int out_size, void* d_ws, size_t ws_size,
                              hipStream_t stream) {
    const float* hs   = (const float*)d_in[0];
    const float* mask = (const float*)d_in[1];
    const float* Wq   = (const float*)d_in[2];
    const float* bq   = (const float*)d_in[3];
    const float* Wk   = (const float*)d_in[4];
    const float* bk   = (const float*)d_in[5];
    const float* Wv   = (const float*)d_in[6];
    const float* bv   = (const float*)d_in[7];
    const float* dist = (const float*)d_in[8];
    float* out = (float*)d_out;

    float* ws = (float*)d_ws;
    const size_t QKV = (size_t)B_ * H_ * S_ * D_;
    const size_t AG  = (size_t)B_ * H_ * A_ * D_;
    float* Q     = ws;
    float* K     = ws + QKV;
    float* V     = ws + 2 * QKV;
    float* Agent = ws + 3 * QKV;     // unused (layout stability)
    float* AgV   = Agent + AG;       // unused (fused away; layout stability)
    float* Pacc  = AgV + AG;
    float* Pm    = Pacc + (size_t)B_ * H_ * CH1 * A_ * D_;
    float* Pl    = Pm + (size_t)B_ * H_ * CH1 * A_;
    unsigned short* Wth = (unsigned short*)(Pl + (size_t)B_ * H_ * CH1 * A_);
    unsigned short* Wtl = Wth + (size_t)3 * HID * HID;
    unsigned short* DFh = Wtl + (size_t)3 * HID * HID;
    unsigned short* DFl = DFh + (size_t)262144;
    unsigned short* AGFh = DFl + (size_t)262144;
    unsigned short* AGFl = AGFh + (size_t)589824;
    unsigned short* AVFh = AGFl + (size_t)589824;
    unsigned short* AVFl = AVFh + (size_t)786432;
    unsigned short* AG1h = AVFl + (size_t)786432;
    unsigned short* AG1l = AG1h + (size_t)589824;
    unsigned short* D0h  = AG1l + (size_t)589824;
    unsigned short* D0l  = D0h + (size_t)134144;
    // total ws ~340 MB (within known-good <=393 MB budget)

    preconvert<<<WT_BLKS + DF_BLKS + D0_BLKS, 256, 0, stream>>>(
        Wq, Wk, Wv, dist, Wth, Wtl, DFh, DFl, D0h, D0l);
    qkv_z<<<2304, 512, 0, stream>>>(hs, Wth, Wtl, bq, bk, bv, Q, K, V);
    agpool_frag<<<B_ * H_, 256, 0, stream>>>(Q, AGFh, AGFl, AG1h, AG1l);
    dim3 g1(CH1, B_ * H_);
    stage1_mfma<<<g1, 256, 0, stream>>>(K, V, AG1h, AG1l, D0h, D0l, mask, Pacc, Pm, Pl);
    stage1_reduce<<<B_ * H_, 256, 0, stream>>>(Pacc, Pm, Pl, AVFh, AVFl);
    dim3 g2(8, B_ * H_);
    stage2_mfma<<<g2, 256, 0, stream>>>(Q, AGFh, AGFl, DFh, DFl, AVFh, AVFl, out);
}